// Round 1
// 1137.243 us; speedup vs baseline: 1.3351x; 1.3351x over previous
//
#include <hip/hip_runtime.h>
#include <math.h>

// ---------------------------------------------------------------------------
// MoE layer, round 8: router atomic de-contention.
// R7 profile: router_kernel = 428 us (28% of total) with VALUBusy 1.3% --
// 32768 f32 atomicAdds all hitting one cache line (loss[0..9]) serialized in
// TCC. Fix: per-block LDS partials -> per-block partial buffer -> reduction
// in finalize_loss. Zero global atomics.
// Main path (gateup, down-proj): split-precision bf16 MFMA (hi/lo, 3 terms).
// Damped paths (adapt, experts): plain bf16 MFMA / f32 VALU. (unchanged)
// B=4, S=2048, D=1024, H=2048, A=128, E=8, N=8192.
// ---------------------------------------------------------------------------

typedef __bf16 bf16_t;
typedef __attribute__((ext_vector_type(8))) __bf16 bf16x8;
typedef __attribute__((ext_vector_type(4))) float f32x4;

__device__ __forceinline__ float b2f(bf16_t v) { return (float)v; }
__device__ __forceinline__ bf16_t f2b(float v) { return (bf16_t)v; }
__device__ __forceinline__ float siluf(float v) { return v / (1.f + expf(-v)); }

static constexpr int Bb = 4, S = 2048, D = 1024, H = 2048, A = 128, E = 8;
static constexpr int N = Bb * S;

// 8 consecutive f32 -> bf16 (plain round)
__device__ __forceinline__ bf16x8 ld8f(const float* p) {
  float4 a = *reinterpret_cast<const float4*>(p);
  float4 b = *reinterpret_cast<const float4*>(p + 4);
  bf16x8 r;
  r[0] = f2b(a.x); r[1] = f2b(a.y); r[2] = f2b(a.z); r[3] = f2b(a.w);
  r[4] = f2b(b.x); r[5] = f2b(b.y); r[6] = f2b(b.z); r[7] = f2b(b.w);
  return r;
}
// 8 consecutive f32 -> hi/lo bf16 split
__device__ __forceinline__ void split8(const float* p, bf16x8& h, bf16x8& l) {
  float4 a = *reinterpret_cast<const float4*>(p);
  float4 b = *reinterpret_cast<const float4*>(p + 4);
  float v[8] = {a.x, a.y, a.z, a.w, b.x, b.y, b.z, b.w};
#pragma unroll
  for (int j = 0; j < 8; j++) {
    bf16_t hh = f2b(v[j]);
    h[j] = hh;
    l[j] = f2b(v[j] - b2f(hh));
  }
}
// mixed loader for plain-bf16 GEMM staging
__device__ __forceinline__ bf16x8 ld8(const void* p, long i, int isf) {
  if (isf) return ld8f(reinterpret_cast<const float*>(p) + i);
  return *reinterpret_cast<const bf16x8*>(reinterpret_cast<const bf16_t*>(p) + i);
}

// ---------------------------------------------------------------------------
// Plain-bf16 NT GEMM (verified layout, R4==R5 bit-identical).
// MODE: 0 bf16 store; 1 silu(clip(v,-5,5)) bf16; 2 f32 RMW C += 0.1*v;
//       3 f32 RMW C = C*aux[row] + 0.1*v
// ---------------------------------------------------------------------------
template <int WM, int WN, int MODE>
__global__ __launch_bounds__(256) void gemm_nt_b(
    const void* __restrict__ Ag, const void* __restrict__ Bg,
    void* __restrict__ Cv, int M, int Nn, int K,
    const float* __restrict__ aux, int aF, int bF) {
  constexpr int BM = 2 * WM, BN = 2 * WN, AM = WM / 16, AN = WN / 16;
  constexpr int LDT = 40;
  __shared__ alignas(16) bf16_t As[BM * LDT];
  __shared__ alignas(16) bf16_t Bs[BN * LDT];

  const int tid = threadIdx.x;
  const int wave = tid >> 6, lane = tid & 63;
  const int wr = wave >> 1, wc = wave & 1;
  const int quad = lane >> 4, l16 = lane & 15;
  const int rowA0 = blockIdx.y * BM, rowB0 = blockIdx.x * BN;

  f32x4 acc[AM][AN] = {};

  for (int k0 = 0; k0 < K; k0 += 32) {
    for (int c = tid; c < BM * 4; c += 256) {
      int r = c >> 2, kc = c & 3;
      *reinterpret_cast<bf16x8*>(&As[r * LDT + kc * 8]) =
          ld8(Ag, (long)(rowA0 + r) * K + k0 + kc * 8, aF);
    }
    for (int c = tid; c < BN * 4; c += 256) {
      int r = c >> 2, kc = c & 3;
      *reinterpret_cast<bf16x8*>(&Bs[r * LDT + kc * 8]) =
          ld8(Bg, (long)(rowB0 + r) * K + k0 + kc * 8, bF);
    }
    __syncthreads();
    bf16x8 af[AM], bfv[AN];
#pragma unroll
    for (int i = 0; i < AM; i++)
      af[i] = *reinterpret_cast<bf16x8*>(&As[(wr * WM + i * 16 + l16) * LDT + quad * 8]);
#pragma unroll
    for (int j = 0; j < AN; j++)
      bfv[j] = *reinterpret_cast<bf16x8*>(&Bs[(wc * WN + j * 16 + l16) * LDT + quad * 8]);
#pragma unroll
    for (int i = 0; i < AM; i++)
#pragma unroll
      for (int j = 0; j < AN; j++)
        acc[i][j] = __builtin_amdgcn_mfma_f32_16x16x32_bf16(af[i], bfv[j], acc[i][j], 0, 0, 0);
    __syncthreads();
  }

  // C/D: col = lane&15, row = quad*4 + reg
#pragma unroll
  for (int i = 0; i < AM; i++)
#pragma unroll
    for (int j = 0; j < AN; j++)
#pragma unroll
      for (int r = 0; r < 4; r++) {
        int row = rowA0 + wr * WM + i * 16 + quad * 4 + r;
        int col = rowB0 + wc * WN + j * 16 + l16;
        long o = (long)row * Nn + col;
        float v = acc[i][j][r];
        if constexpr (MODE == 0) {
          reinterpret_cast<bf16_t*>(Cv)[o] = f2b(v);
        } else if constexpr (MODE == 1) {
          v = fminf(fmaxf(v, -5.f), 5.f);
          reinterpret_cast<bf16_t*>(Cv)[o] = f2b(siluf(v));
        } else if constexpr (MODE == 2) {
          float* C = reinterpret_cast<float*>(Cv);
          C[o] = C[o] + 0.1f * v;
        } else {
          float* C = reinterpret_cast<float*>(Cv);
          C[o] = C[o] * aux[row] + 0.1f * v;
        }
      }
}

// ---------------------------------------------------------------------------
// Split-precision (hi/lo) down-proj GEMM: C_f32 = A_f32 @ B_f32^T.
// 128x128 tile, 3 MFMAs per (i,j) per k-step.
// ---------------------------------------------------------------------------
__global__ __launch_bounds__(256) void gemm_dn_hl(
    const float* __restrict__ Ag, const float* __restrict__ Bg,
    float* __restrict__ Cg, int M, int Nn, int K) {
  constexpr int BM = 128, BN = 128, LDT = 40;
  __shared__ alignas(16) bf16_t Ah[BM * LDT];
  __shared__ alignas(16) bf16_t Al[BM * LDT];
  __shared__ alignas(16) bf16_t Bh[BN * LDT];
  __shared__ alignas(16) bf16_t Bl[BN * LDT];

  const int tid = threadIdx.x;
  const int wave = tid >> 6, lane = tid & 63;
  const int wr = wave >> 1, wc = wave & 1;
  const int quad = lane >> 4, l16 = lane & 15;
  const int rowA0 = blockIdx.y * BM, rowB0 = blockIdx.x * BN;

  f32x4 acc[4][4] = {};

  for (int k0 = 0; k0 < K; k0 += 32) {
    for (int c = tid; c < BM * 4; c += 256) {
      int r = c >> 2, kc = c & 3;
      bf16x8 h, l;
      split8(&Ag[(long)(rowA0 + r) * K + k0 + kc * 8], h, l);
      *reinterpret_cast<bf16x8*>(&Ah[r * LDT + kc * 8]) = h;
      *reinterpret_cast<bf16x8*>(&Al[r * LDT + kc * 8]) = l;
    }
    for (int c = tid; c < BN * 4; c += 256) {
      int r = c >> 2, kc = c & 3;
      bf16x8 h, l;
      split8(&Bg[(long)(rowB0 + r) * K + k0 + kc * 8], h, l);
      *reinterpret_cast<bf16x8*>(&Bh[r * LDT + kc * 8]) = h;
      *reinterpret_cast<bf16x8*>(&Bl[r * LDT + kc * 8]) = l;
    }
    __syncthreads();
    bf16x8 afh[4], afl[4], bfh[4], bfl[4];
#pragma unroll
    for (int i = 0; i < 4; i++) {
      int ro = (wr * 64 + i * 16 + l16) * LDT + quad * 8;
      afh[i] = *reinterpret_cast<bf16x8*>(&Ah[ro]);
      afl[i] = *reinterpret_cast<bf16x8*>(&Al[ro]);
    }
#pragma unroll
    for (int j = 0; j < 4; j++) {
      int ro = (wc * 64 + j * 16 + l16) * LDT + quad * 8;
      bfh[j] = *reinterpret_cast<bf16x8*>(&Bh[ro]);
      bfl[j] = *reinterpret_cast<bf16x8*>(&Bl[ro]);
    }
#pragma unroll
    for (int i = 0; i < 4; i++)
#pragma unroll
      for (int j = 0; j < 4; j++) {
        acc[i][j] = __builtin_amdgcn_mfma_f32_16x16x32_bf16(afh[i], bfh[j], acc[i][j], 0, 0, 0);
        acc[i][j] = __builtin_amdgcn_mfma_f32_16x16x32_bf16(afh[i], bfl[j], acc[i][j], 0, 0, 0);
        acc[i][j] = __builtin_amdgcn_mfma_f32_16x16x32_bf16(afl[i], bfh[j], acc[i][j], 0, 0, 0);
      }
    __syncthreads();
  }

#pragma unroll
  for (int i = 0; i < 4; i++)
#pragma unroll
    for (int j = 0; j < 4; j++)
#pragma unroll
      for (int r = 0; r < 4; r++) {
        int row = rowA0 + wr * 64 + i * 16 + quad * 4 + r;
        int col = rowB0 + wc * 64 + j * 16 + l16;
        Cg[(long)row * Nn + col] = acc[i][j][r];
      }
}

// ---------------------------------------------------------------------------
// Split-precision fused gate/up: hidden_f32 = silu(x@Wg^T)*(x@Wu^T).
// 128x64 tile; 6 MFMAs per (i,j) per k-step.
// ---------------------------------------------------------------------------
__global__ __launch_bounds__(256) void gemm_gu_hl(
    const float* __restrict__ x, const float* __restrict__ Wg,
    const float* __restrict__ Wu, float* __restrict__ Cg, int M, int Nn, int K) {
  constexpr int BM = 128, BN = 64, LDT = 40;
  __shared__ alignas(16) bf16_t Ah[BM * LDT];
  __shared__ alignas(16) bf16_t Al[BM * LDT];
  __shared__ alignas(16) bf16_t B1h[BN * LDT];
  __shared__ alignas(16) bf16_t B1l[BN * LDT];
  __shared__ alignas(16) bf16_t B2h[BN * LDT];
  __shared__ alignas(16) bf16_t B2l[BN * LDT];

  const int tid = threadIdx.x;
  const int wave = tid >> 6, lane = tid & 63;
  const int wr = wave >> 1, wc = wave & 1;
  const int quad = lane >> 4, l16 = lane & 15;
  const int rowA0 = blockIdx.y * BM, rowB0 = blockIdx.x * BN;

  f32x4 ag[4][2] = {}, au[4][2] = {};

  for (int k0 = 0; k0 < K; k0 += 32) {
    for (int c = tid; c < BM * 4; c += 256) {
      int r = c >> 2, kc = c & 3;
      bf16x8 h, l;
      split8(&x[(long)(rowA0 + r) * K + k0 + kc * 8], h, l);
      *reinterpret_cast<bf16x8*>(&Ah[r * LDT + kc * 8]) = h;
      *reinterpret_cast<bf16x8*>(&Al[r * LDT + kc * 8]) = l;
    }
    for (int c = tid; c < BN * 4; c += 256) {
      int r = c >> 2, kc = c & 3;
      long idx = (long)(rowB0 + r) * K + k0 + kc * 8;
      bf16x8 h, l;
      split8(&Wg[idx], h, l);
      *reinterpret_cast<bf16x8*>(&B1h[r * LDT + kc * 8]) = h;
      *reinterpret_cast<bf16x8*>(&B1l[r * LDT + kc * 8]) = l;
      split8(&Wu[idx], h, l);
      *reinterpret_cast<bf16x8*>(&B2h[r * LDT + kc * 8]) = h;
      *reinterpret_cast<bf16x8*>(&B2l[r * LDT + kc * 8]) = l;
    }
    __syncthreads();
    bf16x8 afh[4], afl[4], b1h[2], b1l[2], b2h[2], b2l[2];
#pragma unroll
    for (int i = 0; i < 4; i++) {
      int ro = (wr * 64 + i * 16 + l16) * LDT + quad * 8;
      afh[i] = *reinterpret_cast<bf16x8*>(&Ah[ro]);
      afl[i] = *reinterpret_cast<bf16x8*>(&Al[ro]);
    }
#pragma unroll
    for (int j = 0; j < 2; j++) {
      int ro = (wc * 32 + j * 16 + l16) * LDT + quad * 8;
      b1h[j] = *reinterpret_cast<bf16x8*>(&B1h[ro]);
      b1l[j] = *reinterpret_cast<bf16x8*>(&B1l[ro]);
      b2h[j] = *reinterpret_cast<bf16x8*>(&B2h[ro]);
      b2l[j] = *reinterpret_cast<bf16x8*>(&B2l[ro]);
    }
#pragma unroll
    for (int i = 0; i < 4; i++)
#pragma unroll
      for (int j = 0; j < 2; j++) {
        ag[i][j] = __builtin_amdgcn_mfma_f32_16x16x32_bf16(afh[i], b1h[j], ag[i][j], 0, 0, 0);
        ag[i][j] = __builtin_amdgcn_mfma_f32_16x16x32_bf16(afh[i], b1l[j], ag[i][j], 0, 0, 0);
        ag[i][j] = __builtin_amdgcn_mfma_f32_16x16x32_bf16(afl[i], b1h[j], ag[i][j], 0, 0, 0);
        au[i][j] = __builtin_amdgcn_mfma_f32_16x16x32_bf16(afh[i], b2h[j], au[i][j], 0, 0, 0);
        au[i][j] = __builtin_amdgcn_mfma_f32_16x16x32_bf16(afh[i], b2l[j], au[i][j], 0, 0, 0);
        au[i][j] = __builtin_amdgcn_mfma_f32_16x16x32_bf16(afl[i], b2h[j], au[i][j], 0, 0, 0);
      }
    __syncthreads();
  }

#pragma unroll
  for (int i = 0; i < 4; i++)
#pragma unroll
    for (int j = 0; j < 2; j++)
#pragma unroll
      for (int r = 0; r < 4; r++) {
        int row = rowA0 + wr * 64 + i * 16 + quad * 4 + r;
        int col = rowB0 + wc * 32 + j * 16 + l16;
        Cg[(long)row * Nn + col] = siluf(ag[i][j][r]) * au[i][j][r];
      }
}

// ---------------------------------------------------------------------------
// Router, R8: NO global atomics. Per-wave loss contributions -> LDS ->
// per-block 12-float partial record in lpart. Deterministic.
// lpart layout per block: [0..7] expert load, [8] gl^2 sum, [9] el^2 sum.
// ---------------------------------------------------------------------------
__global__ __launch_bounds__(256) void router_kernel(
    const float* __restrict__ x, const float* __restrict__ Wgr,
    const float* __restrict__ Wer, int* __restrict__ eidx,
    float* __restrict__ fw, float* __restrict__ wsum,
    float* __restrict__ lpart) {
  __shared__ float part[4][12];
  const int wv = threadIdx.x >> 6;
  const int lane = threadIdx.x & 63;
  const int token = blockIdx.x * 4 + wv;
  if (lane < 12) part[wv][lane] = 0.f;  // wave-local zeroing, ordered before lane-0 writes
  const float* xp = x + (long)token * D;
  float xr[16];
#pragma unroll
  for (int i = 0; i < 16; i++) xr[i] = xp[lane + i * 64];
  float dots[6];
#pragma unroll
  for (int w = 0; w < 6; w++) {
    const float* wp = (w < 2) ? (Wgr + (long)w * D) : (Wer + (long)(w - 2) * D);
    float s = 0.f;
#pragma unroll
    for (int i = 0; i < 16; i++) s += xr[i] * wp[lane + i * 64];
#pragma unroll
    for (int off = 32; off; off >>= 1) s += __shfl_xor(s, off);
    dots[w] = s;
  }
  if (lane == 0) {
    float gl0 = dots[0], gl1 = dots[1];
    float mg = fmaxf(gl0, gl1);
    float e0 = expf(gl0 - mg), e1 = expf(gl1 - mg);
    float inv = 1.f / (e0 + e1);
    float gp0 = e0 * inv, gp1 = e1 * inv;
    int gi = (gp1 > gp0) ? 1 : 0;
    float gw = gi ? gp1 : gp0;
    float el[4] = {dots[2], dots[3], dots[4], dots[5]};
    float me = fmaxf(fmaxf(el[0], el[1]), fmaxf(el[2], el[3]));
    float ep[4], es = 0.f;
#pragma unroll
    for (int j = 0; j < 4; j++) { ep[j] = expf(el[j] - me); es += ep[j]; }
    float inve = 1.f / es;
#pragma unroll
    for (int j = 0; j < 4; j++) ep[j] *= inve;
    int i1 = 0;
    for (int j = 1; j < 4; j++) if (ep[j] > ep[i1]) i1 = j;
    int i2 = (i1 == 0) ? 1 : 0;
    for (int j = 0; j < 4; j++) if (j != i1 && j != i2 && ep[j] > ep[i2]) i2 = j;
    float l1 = ep[i1], l2 = ep[i2];
    float ils = 1.f / (l1 + l2 + 1e-7f);
    float f1 = gw * l1 * ils, f2 = gw * l2 * ils;
    eidx[token * 2] = gi * 4 + i1;
    eidx[token * 2 + 1] = gi * 4 + i2;
    fw[token * 2] = f1;
    fw[token * 2 + 1] = f2;
    wsum[token] = f1 + f2;
    // i1 != i2 always -> distinct LDS slots, plain stores
    part[wv][gi * 4 + i1] = f1;
    part[wv][gi * 4 + i2] = f2;
    part[wv][8] = gl0 * gl0 + gl1 * gl1;
    part[wv][9] = el[0] * el[0] + el[1] * el[1] + el[2] * el[2] + el[3] * el[3];
  }
  __syncthreads();
  if (threadIdx.x < 12) {
    lpart[(long)blockIdx.x * 12 + threadIdx.x] =
        part[0][threadIdx.x] + part[1][threadIdx.x] +
        part[2][threadIdx.x] + part[3][threadIdx.x];
  }
}

// ---------------------------------------------------------------------------
// Row LayerNorm over A=128 (bf16 in ws, f32 g/b, bf16 out).
// ---------------------------------------------------------------------------
__global__ __launch_bounds__(256) void ln_rows(
    const bf16_t* __restrict__ in, const float* __restrict__ g,
    const float* __restrict__ b, bf16_t* __restrict__ out) {
  const int row = blockIdx.x * 4 + (threadIdx.x >> 6);
  const int lane = threadIdx.x & 63;
  const bf16_t* p = in + (long)row * A;
  float x0 = b2f(p[lane]), x1 = b2f(p[lane + 64]);
  float s = x0 + x1;
#pragma unroll
  for (int off = 32; off; off >>= 1) s += __shfl_xor(s, off);
  float mean = s * (1.f / 128.f);
  float d0 = x0 - mean, d1 = x1 - mean;
  float q = d0 * d0 + d1 * d1;
#pragma unroll
  for (int off = 32; off; off >>= 1) q += __shfl_xor(q, off);
  float r = rsqrtf(q * (1.f / 128.f) + 1e-5f);
  bf16_t* po = out + (long)row * A;
  po[lane] = f2b(d0 * r * g[lane] + b[lane]);
  po[lane + 64] = f2b(d1 * r * g[lane + 64] + b[lane + 64]);
}

// ---------------------------------------------------------------------------
// Transpose [z,R,C] -> [z,C,R], bf16 out; input f32 (isf=1) or bf16.
// ---------------------------------------------------------------------------
__global__ __launch_bounds__(256) void transpose2d(
    const void* __restrict__ in, bf16_t* __restrict__ out, int R, int C, int isf) {
  __shared__ bf16_t t[32][33];
  const long zb = blockIdx.z;
  const long ib = zb * (long)R * C;
  bf16_t* op = out + zb * (long)R * C;
  const int r0 = blockIdx.y * 32, c0 = blockIdx.x * 32;
  const int tx = threadIdx.x & 31, ty = threadIdx.x >> 5;
#pragma unroll
  for (int i = 0; i < 4; i++) {
    long idx = ib + (long)(r0 + ty + i * 8) * C + c0 + tx;
    t[ty + i * 8][tx] = isf ? f2b(reinterpret_cast<const float*>(in)[idx])
                            : reinterpret_cast<const bf16_t*>(in)[idx];
  }
  __syncthreads();
#pragma unroll
  for (int i = 0; i < 4; i++) op[(long)(c0 + ty + i * 8) * R + r0 + tx] = t[tx][ty + i * 8];
}

// ---------------------------------------------------------------------------
// Expert branch (f32 math, h0 from bf16 ws).
// ---------------------------------------------------------------------------
__global__ __launch_bounds__(128) void expert_adapt(
    const bf16_t* __restrict__ h0, const float* __restrict__ Wea,
    const float* __restrict__ ln_eg, const float* __restrict__ ln_eb,
    const int* __restrict__ eidx, const float* __restrict__ fw,
    bf16_t* __restrict__ hw) {
  const int n = blockIdx.x;
  const int c = threadIdx.x;
  __shared__ float h0s[128];
  __shared__ float red[4];
  h0s[c] = b2f(h0[(long)n * A + c]);
  __syncthreads();
  float out = 0.f;
  for (int k = 0; k < 2; k++) {
    int e = eidx[n * 2 + k];
    e = min(max(e, 0), E - 1);
    float w = fw[n * 2 + k];
    const float* Wr = Wea + ((long)e * A + c) * A;
    float t = 0.f;
#pragma unroll 8
    for (int a = 0; a < 128; a++) t += Wr[a] * h0s[a];
    float s = t, q = t * t;
#pragma unroll
    for (int off = 32; off; off >>= 1) { s += __shfl_xor(s, off); q += __shfl_xor(q, off); }
    if ((c & 63) == 0) { red[(c >> 6) * 2] = s; red[(c >> 6) * 2 + 1] = q; }
    __syncthreads();
    float Sx = red[0] + red[2], Qx = red[1] + red[3];
    float mean = Sx * (1.f / 128.f);
    float var = Qx * (1.f / 128.f) - mean * mean;
    float r = rsqrtf(var + 1e-5f);
    out += w * ((t - mean) * r * ln_eg[e * A + c] + ln_eb[e * A + c]);
    __syncthreads();
  }
  hw[(long)n * A + c] = f2b(out);
}

// ---------------------------------------------------------------------------
// Loss finalize, R8: reduce 2048 per-block 12-float partials, then scalar.
// ---------------------------------------------------------------------------
__global__ __launch_bounds__(256) void finalize_loss(
    const float* __restrict__ lpart, int nblk, float* __restrict__ outv) {
  float acc[10] = {};
  for (int b = threadIdx.x; b < nblk; b += 256) {
    const float* p = lpart + (long)b * 12;
#pragma unroll
    for (int c = 0; c < 10; c++) acc[c] += p[c];
  }
  __shared__ float red[10][4];
  const int lane = threadIdx.x & 63, wv = threadIdx.x >> 6;
#pragma unroll
  for (int c = 0; c < 10; c++) {
    float s = acc[c];
#pragma unroll
    for (int off = 32; off; off >>= 1) s += __shfl_xor(s, off);
    if (lane == 0) red[c][wv] = s;
  }
  __syncthreads();
  if (threadIdx.x == 0) {
    float loss[10];
#pragma unroll
    for (int c = 0; c < 10; c++)
      loss[c] = red[c][0] + red[c][1] + red[c][2] + red[c][3];
    float tl = 0.f;
    for (int e = 0; e < 8; e++) tl += loss[e];
    float target = tl / 8.f;
    float mse = 0.f;
    for (int e = 0; e < 8; e++) { float d = loss[e] - target; mse += d * d; }
    mse *= (1.f / 8.f);
    outv[0] = 0.001f * (mse + loss[8] / (float)(N * 2) + loss[9] / (float)(N * 4));
  }
}

// ---------------------------------------------------------------------------
extern "C" void kernel_launch(void* const* d_in, const int* in_sizes, int n_in,
                              void* d_out, int out_size, void* d_ws, size_t ws_size,
                              hipStream_t stream) {
  const float* x = (const float*)d_in[0];
  const float* Wu = (const float*)d_in[1];
  const float* Wg = (const float*)d_in[2];
  const float* Wd = (const float*)d_in[3];
  const float* Wpre = (const float*)d_in[4];
  const float* Wpost = (const float*)d_in[5];
  const float* ln_g = (const float*)d_in[6];
  const float* ln_b = (const float*)d_in[7];
  const float* Wap = (const float*)d_in[8];
  const float* Wea = (const float*)d_in[9];
  const float* ln_eg = (const float*)d_in[10];
  const float* ln_eb = (const float*)d_in[11];
  const float* Wep = (const float*)d_in[12];
  const float* Wop = (const float*)d_in[13];
  const float* Wgr = (const float*)d_in[14];
  const float* Wer = (const float*)d_in[15];
  float* out = (float*)d_out;

  // Workspace ~83 MB (ws >= ~91 MB proven by R3/R4 equivalence).
  char* ws = (char*)d_ws;
  size_t off = 0;
  auto alloc = [&](size_t bytes) { char* p = ws + off; off += (bytes + 255) & ~size_t(255); return p; };
  float* lpart = (float*)alloc((size_t)(N / 4) * 12 * 4);  // 96 KB per-block loss partials
  float* wsum = (float*)alloc((size_t)N * 4);
  float* fwb = (float*)alloc((size_t)N * 2 * 4);
  int* eidx = (int*)alloc((size_t)N * 2 * 4);
  bf16_t* Mb = (bf16_t*)alloc((size_t)D * A * 2);      // 256 KB
  bf16_t* WepT = (bf16_t*)alloc((size_t)H * A * 2);    // 512 KB
  bf16_t* hwb = (bf16_t*)alloc((size_t)N * A * 2);     // 2 MB
  bf16_t* h0b = (bf16_t*)alloc((size_t)N * A * 2);     // 2 MB
  bf16_t* aib = (bf16_t*)alloc((size_t)N * A * 2);     // 2 MB
  bf16_t* scrA = (bf16_t*)alloc((size_t)N * A * 2);    // 2 MB  (aopre -> aiT)
  bf16_t* scrB = (bf16_t*)alloc((size_t)N * A * 2);    // 2 MB  (aob -> adpre)
  bf16_t* awb = (bf16_t*)alloc((size_t)S * S * 2);     // 8 MB  (one batch)
  float* hiddenF = (float*)alloc((size_t)N * H * 4);   // 64 MB
  bf16_t* aopre = scrA;
  bf16_t* aiT = scrA;
  bf16_t* aob = scrB;
  bf16_t* adpre = scrB;
  (void)ws_size; (void)in_sizes; (void)n_in; (void)out_size;

  const dim3 blk(256);

  router_kernel<<<dim3(N / 4), blk, 0, stream>>>(x, Wgr, Wer, eidx, fwb, wsum, lpart);
  // hidden = silu(x@Wg^T)*(x@Wu^T)  f32, split-precision  [N,H] K=D
  gemm_gu_hl<<<dim3(H / 64, N / 128), blk, 0, stream>>>(x, Wg, Wu, hiddenF, N, H, D);
  // h0 = x@Wpre^T  [N,A] K=D (plain bf16)
  gemm_nt_b<32, 32, 0><<<dim3(A / 64, N / 64), blk, 0, stream>>>(
      x, Wpre, h0b, N, A, D, nullptr, 1, 1);
  ln_rows<<<dim3(N / 4), blk, 0, stream>>>(h0b, ln_g, ln_b, aib);
  // ao_pre = hidden@Wpost^T  [N,A] K=H (plain bf16; A from f32 hidden)
  gemm_nt_b<32, 32, 0><<<dim3(A / 64, N / 64), blk, 0, stream>>>(
      hiddenF, Wpost, aopre, N, A, H, nullptr, 1, 1);
  ln_rows<<<dim3(N / 4), blk, 0, stream>>>(aopre, ln_g, ln_b, aob);
  // aiT = ai^T per batch
  transpose2d<<<dim3(A / 32, S / 32, Bb), blk, 0, stream>>>(aib, aiT, S, A, 0);
  // per batch: aw_b = silu(clip(ai_b@ao_b^T)); adpre_b = aw_b@aiT_b^T
  for (int b = 0; b < Bb; b++) {
    const bf16_t* ai_b = aib + (size_t)b * S * A;
    const bf16_t* ao_b = aob + (size_t)b * S * A;
    const bf16_t* aiT_b = aiT + (size_t)b * A * S;
    bf16_t* adpre_b = adpre + (size_t)b * S * A;
    gemm_nt_b<64, 64, 1><<<dim3(S / 128, S / 128), blk, 0, stream>>>(
        ai_b, ao_b, awb, S, S, A, nullptr, 0, 0);
    gemm_nt_b<32, 32, 0><<<dim3(A / 64, S / 64), blk, 0, stream>>>(
        awb, aiT_b, adpre_b, S, A, S, nullptr, 0, 0);
  }
  // hidden += 0.1 * adpre@Wap^T  [N,H] K=A (f32 RMW)
  gemm_nt_b<64, 64, 2><<<dim3(H / 128, N / 128), blk, 0, stream>>>(
      adpre, Wap, hiddenF, N, H, A, nullptr, 0, 1);
  // out = shared = hidden@Wd^T  f32, split-precision  [N,D] K=H
  gemm_dn_hl<<<dim3(D / 128, N / 128), blk, 0, stream>>>(hiddenF, Wd, out, N, D, H);
  // WepT = Wep^T (f32 -> bf16)
  transpose2d<<<dim3(A / 32, H / 32, 1), blk, 0, stream>>>(Wep, WepT, H, A, 1);
  // M = Wop@Wep  [D,A] K=H (plain bf16)
  gemm_nt_b<32, 32, 0><<<dim3(A / 64, D / 64), blk, 0, stream>>>(
      Wop, WepT, Mb, D, A, H, nullptr, 1, 0);
  // hw = sum_k fw_k * LN_e(Wea[e_k]@h0)
  expert_adapt<<<dim3(N), dim3(128), 0, stream>>>(h0b, Wea, ln_eg, ln_eb, eidx, fwb, hwb);
  // out = out*wsum[row] + 0.1*hw@M^T  [N,D] K=A (f32 in-place RMW)
  gemm_nt_b<64, 64, 3><<<dim3(D / 128, N / 128), blk, 0, stream>>>(
      hwb, Mb, out, N, D, A, wsum, 0, 0);
  finalize_loss<<<dim3(1), blk, 0, stream>>>(lpart, N / 4, out + (size_t)N * D);
}

// Round 3
// 983.507 us; speedup vs baseline: 1.5438x; 1.1563x over previous
//
#include <hip/hip_runtime.h>
#include <math.h>

// ---------------------------------------------------------------------------
// MoE layer, round 10 == round 9 resubmit (R9 bench died to container infra,
// no pass/fail produced; code audit found no OOB/fault path).
// R9 change log: hoist hi/lo split out of GEMM k-loops.
//   R8 profile: gemm_gu_hl 257us @ MfmaUtil 36 / VALUBusy 40 / 21% bank-
//   conflict cycles; split8 in staging = 144 VALU/thread/kstep, re-done per
//   tile. Fix: pre-split x,Wg,Wu,Wd to hi/lo bf16 once; hidden lives as
//   Hh/Hl bf16 pair (no f32 hiddenF). GEMM staging becomes pure 16B copies.
//   Needs ~139.3MiB ws -> gated on ws_size >= 140MiB, proven R8 fallback.
//   Also: expert_adapt was fully uncoalesced (512B thread stride on Wea);
//   pre-transpose to WeaT[e][a][c] bf16 -> coalesced (both paths).
// B=4, S=2048, D=1024, H=2048, A=128, E=8, N=8192.
// ---------------------------------------------------------------------------

typedef __bf16 bf16_t;
typedef __attribute__((ext_vector_type(8))) __bf16 bf16x8;
typedef __attribute__((ext_vector_type(4))) float f32x4;

__device__ __forceinline__ float b2f(bf16_t v) { return (float)v; }
__device__ __forceinline__ bf16_t f2b(float v) { return (bf16_t)v; }
__device__ __forceinline__ float siluf(float v) { return v / (1.f + expf(-v)); }

static constexpr int Bb = 4, S = 2048, D = 1024, H = 2048, A = 128, E = 8;
static constexpr int N = Bb * S;

// 8 consecutive f32 -> bf16 (plain round)
__device__ __forceinline__ bf16x8 ld8f(const float* p) {
  float4 a = *reinterpret_cast<const float4*>(p);
  float4 b = *reinterpret_cast<const float4*>(p + 4);
  bf16x8 r;
  r[0] = f2b(a.x); r[1] = f2b(a.y); r[2] = f2b(a.z); r[3] = f2b(a.w);
  r[4] = f2b(b.x); r[5] = f2b(b.y); r[6] = f2b(b.z); r[7] = f2b(b.w);
  return r;
}
// 8 consecutive f32 -> hi/lo bf16 split
__device__ __forceinline__ void split8(const float* p, bf16x8& h, bf16x8& l) {
  float4 a = *reinterpret_cast<const float4*>(p);
  float4 b = *reinterpret_cast<const float4*>(p + 4);
  float v[8] = {a.x, a.y, a.z, a.w, b.x, b.y, b.z, b.w};
#pragma unroll
  for (int j = 0; j < 8; j++) {
    bf16_t hh = f2b(v[j]);
    h[j] = hh;
    l[j] = f2b(v[j] - b2f(hh));
  }
}
// mixed loader for plain-bf16 GEMM staging
__device__ __forceinline__ bf16x8 ld8(const void* p, long i, int isf) {
  if (isf) return ld8f(reinterpret_cast<const float*>(p) + i);
  return *reinterpret_cast<const bf16x8*>(reinterpret_cast<const bf16_t*>(p) + i);
}

// ---------------------------------------------------------------------------
// Elementwise f32 -> hi/lo bf16 split pass (grid-stride over groups of 8).
// ---------------------------------------------------------------------------
__global__ __launch_bounds__(256) void split_pass(
    const float* __restrict__ in, bf16_t* __restrict__ hi,
    bf16_t* __restrict__ lo, long n8) {
  long stride = (long)gridDim.x * blockDim.x;
  for (long i = (long)blockIdx.x * blockDim.x + threadIdx.x; i < n8; i += stride) {
    bf16x8 h, l;
    split8(in + i * 8, h, l);
    reinterpret_cast<bf16x8*>(hi)[i] = h;
    reinterpret_cast<bf16x8*>(lo)[i] = l;
  }
}

// ---------------------------------------------------------------------------
// Plain-bf16 NT GEMM (verified layout).
// MODE: 0 bf16 store; 1 silu(clip(v,-5,5)) bf16; 2 f32 RMW C += 0.1*v;
//       3 f32 RMW C = C*aux[row] + 0.1*v;
//       4 hi/lo bf16 RMW: s = (Ch+Cl) + 0.1*v; Ch,Cl = split(s)
// ---------------------------------------------------------------------------
template <int WM, int WN, int MODE>
__global__ __launch_bounds__(256) void gemm_nt_b(
    const void* __restrict__ Ag, const void* __restrict__ Bg,
    void* __restrict__ Cv, void* __restrict__ Cv2, int M, int Nn, int K,
    const float* __restrict__ aux, int aF, int bF) {
  constexpr int BM = 2 * WM, BN = 2 * WN, AM = WM / 16, AN = WN / 16;
  constexpr int LDT = 40;
  __shared__ alignas(16) bf16_t As[BM * LDT];
  __shared__ alignas(16) bf16_t Bs[BN * LDT];

  const int tid = threadIdx.x;
  const int wave = tid >> 6, lane = tid & 63;
  const int wr = wave >> 1, wc = wave & 1;
  const int quad = lane >> 4, l16 = lane & 15;
  const int rowA0 = blockIdx.y * BM, rowB0 = blockIdx.x * BN;

  f32x4 acc[AM][AN] = {};

  for (int k0 = 0; k0 < K; k0 += 32) {
    for (int c = tid; c < BM * 4; c += 256) {
      int r = c >> 2, kc = c & 3;
      *reinterpret_cast<bf16x8*>(&As[r * LDT + kc * 8]) =
          ld8(Ag, (long)(rowA0 + r) * K + k0 + kc * 8, aF);
    }
    for (int c = tid; c < BN * 4; c += 256) {
      int r = c >> 2, kc = c & 3;
      *reinterpret_cast<bf16x8*>(&Bs[r * LDT + kc * 8]) =
          ld8(Bg, (long)(rowB0 + r) * K + k0 + kc * 8, bF);
    }
    __syncthreads();
    bf16x8 af[AM], bfv[AN];
#pragma unroll
    for (int i = 0; i < AM; i++)
      af[i] = *reinterpret_cast<bf16x8*>(&As[(wr * WM + i * 16 + l16) * LDT + quad * 8]);
#pragma unroll
    for (int j = 0; j < AN; j++)
      bfv[j] = *reinterpret_cast<bf16x8*>(&Bs[(wc * WN + j * 16 + l16) * LDT + quad * 8]);
#pragma unroll
    for (int i = 0; i < AM; i++)
#pragma unroll
      for (int j = 0; j < AN; j++)
        acc[i][j] = __builtin_amdgcn_mfma_f32_16x16x32_bf16(af[i], bfv[j], acc[i][j], 0, 0, 0);
    __syncthreads();
  }

  // C/D: col = lane&15, row = quad*4 + reg
#pragma unroll
  for (int i = 0; i < AM; i++)
#pragma unroll
    for (int j = 0; j < AN; j++)
#pragma unroll
      for (int r = 0; r < 4; r++) {
        int row = rowA0 + wr * WM + i * 16 + quad * 4 + r;
        int col = rowB0 + wc * WN + j * 16 + l16;
        long o = (long)row * Nn + col;
        float v = acc[i][j][r];
        if constexpr (MODE == 0) {
          reinterpret_cast<bf16_t*>(Cv)[o] = f2b(v);
        } else if constexpr (MODE == 1) {
          v = fminf(fmaxf(v, -5.f), 5.f);
          reinterpret_cast<bf16_t*>(Cv)[o] = f2b(siluf(v));
        } else if constexpr (MODE == 2) {
          float* C = reinterpret_cast<float*>(Cv);
          C[o] = C[o] + 0.1f * v;
        } else if constexpr (MODE == 3) {
          float* C = reinterpret_cast<float*>(Cv);
          C[o] = C[o] * aux[row] + 0.1f * v;
        } else {
          bf16_t* Ch = reinterpret_cast<bf16_t*>(Cv);
          bf16_t* Cl = reinterpret_cast<bf16_t*>(Cv2);
          float s = b2f(Ch[o]) + b2f(Cl[o]) + 0.1f * v;
          bf16_t hh = f2b(s);
          Ch[o] = hh;
          Cl[o] = f2b(s - b2f(hh));
        }
      }
}

// ---------------------------------------------------------------------------
// Split-precision (hi/lo) down-proj GEMM, f32 input (fallback path).
// ---------------------------------------------------------------------------
__global__ __launch_bounds__(256) void gemm_dn_hl(
    const float* __restrict__ Ag, const float* __restrict__ Bg,
    float* __restrict__ Cg, int M, int Nn, int K) {
  constexpr int BM = 128, BN = 128, LDT = 40;
  __shared__ alignas(16) bf16_t Ah[BM * LDT];
  __shared__ alignas(16) bf16_t Al[BM * LDT];
  __shared__ alignas(16) bf16_t Bh[BN * LDT];
  __shared__ alignas(16) bf16_t Bl[BN * LDT];

  const int tid = threadIdx.x;
  const int wave = tid >> 6, lane = tid & 63;
  const int wr = wave >> 1, wc = wave & 1;
  const int quad = lane >> 4, l16 = lane & 15;
  const int rowA0 = blockIdx.y * BM, rowB0 = blockIdx.x * BN;

  f32x4 acc[4][4] = {};

  for (int k0 = 0; k0 < K; k0 += 32) {
    for (int c = tid; c < BM * 4; c += 256) {
      int r = c >> 2, kc = c & 3;
      bf16x8 h, l;
      split8(&Ag[(long)(rowA0 + r) * K + k0 + kc * 8], h, l);
      *reinterpret_cast<bf16x8*>(&Ah[r * LDT + kc * 8]) = h;
      *reinterpret_cast<bf16x8*>(&Al[r * LDT + kc * 8]) = l;
    }
    for (int c = tid; c < BN * 4; c += 256) {
      int r = c >> 2, kc = c & 3;
      bf16x8 h, l;
      split8(&Bg[(long)(rowB0 + r) * K + k0 + kc * 8], h, l);
      *reinterpret_cast<bf16x8*>(&Bh[r * LDT + kc * 8]) = h;
      *reinterpret_cast<bf16x8*>(&Bl[r * LDT + kc * 8]) = l;
    }
    __syncthreads();
    bf16x8 afh[4], afl[4], bfh[4], bfl[4];
#pragma unroll
    for (int i = 0; i < 4; i++) {
      int ro = (wr * 64 + i * 16 + l16) * LDT + quad * 8;
      afh[i] = *reinterpret_cast<bf16x8*>(&Ah[ro]);
      afl[i] = *reinterpret_cast<bf16x8*>(&Al[ro]);
    }
#pragma unroll
    for (int j = 0; j < 4; j++) {
      int ro = (wc * 64 + j * 16 + l16) * LDT + quad * 8;
      bfh[j] = *reinterpret_cast<bf16x8*>(&Bh[ro]);
      bfl[j] = *reinterpret_cast<bf16x8*>(&Bl[ro]);
    }
#pragma unroll
    for (int i = 0; i < 4; i++)
#pragma unroll
      for (int j = 0; j < 4; j++) {
        acc[i][j] = __builtin_amdgcn_mfma_f32_16x16x32_bf16(afh[i], bfh[j], acc[i][j], 0, 0, 0);
        acc[i][j] = __builtin_amdgcn_mfma_f32_16x16x32_bf16(afh[i], bfl[j], acc[i][j], 0, 0, 0);
        acc[i][j] = __builtin_amdgcn_mfma_f32_16x16x32_bf16(afl[i], bfh[j], acc[i][j], 0, 0, 0);
      }
    __syncthreads();
  }

#pragma unroll
  for (int i = 0; i < 4; i++)
#pragma unroll
    for (int j = 0; j < 4; j++)
#pragma unroll
      for (int r = 0; r < 4; r++) {
        int row = rowA0 + wr * 64 + i * 16 + quad * 4 + r;
        int col = rowB0 + wc * 64 + j * 16 + l16;
        Cg[(long)row * Nn + col] = acc[i][j][r];
      }
}

// ---------------------------------------------------------------------------
// Down-proj GEMM from PRE-SPLIT hi/lo bf16 inputs (big-ws path).
// Staging is pure 16B copies; 3 MFMAs per (i,j) per k-step.
// ---------------------------------------------------------------------------
__global__ __launch_bounds__(256) void gemm_dn_b(
    const bf16_t* __restrict__ Ahg, const bf16_t* __restrict__ Alg,
    const bf16_t* __restrict__ Bhg, const bf16_t* __restrict__ Blg,
    float* __restrict__ Cg, int M, int Nn, int K) {
  constexpr int BM = 128, BN = 128, LDT = 40;
  __shared__ alignas(16) bf16_t Ah[BM * LDT];
  __shared__ alignas(16) bf16_t Al[BM * LDT];
  __shared__ alignas(16) bf16_t Bh[BN * LDT];
  __shared__ alignas(16) bf16_t Bl[BN * LDT];

  const int tid = threadIdx.x;
  const int wave = tid >> 6, lane = tid & 63;
  const int wr = wave >> 1, wc = wave & 1;
  const int quad = lane >> 4, l16 = lane & 15;
  const int rowA0 = blockIdx.y * BM, rowB0 = blockIdx.x * BN;

  f32x4 acc[4][4] = {};

  for (int k0 = 0; k0 < K; k0 += 32) {
    for (int c = tid; c < BM * 4; c += 256) {
      int r = c >> 2, kc = c & 3;
      long idx = (long)(rowA0 + r) * K + k0 + kc * 8;
      int lo = r * LDT + kc * 8;
      *reinterpret_cast<bf16x8*>(&Ah[lo]) = *reinterpret_cast<const bf16x8*>(&Ahg[idx]);
      *reinterpret_cast<bf16x8*>(&Al[lo]) = *reinterpret_cast<const bf16x8*>(&Alg[idx]);
    }
    for (int c = tid; c < BN * 4; c += 256) {
      int r = c >> 2, kc = c & 3;
      long idx = (long)(rowB0 + r) * K + k0 + kc * 8;
      int lo = r * LDT + kc * 8;
      *reinterpret_cast<bf16x8*>(&Bh[lo]) = *reinterpret_cast<const bf16x8*>(&Bhg[idx]);
      *reinterpret_cast<bf16x8*>(&Bl[lo]) = *reinterpret_cast<const bf16x8*>(&Blg[idx]);
    }
    __syncthreads();
    bf16x8 afh[4], afl[4], bfh[4], bfl[4];
#pragma unroll
    for (int i = 0; i < 4; i++) {
      int ro = (wr * 64 + i * 16 + l16) * LDT + quad * 8;
      afh[i] = *reinterpret_cast<bf16x8*>(&Ah[ro]);
      afl[i] = *reinterpret_cast<bf16x8*>(&Al[ro]);
    }
#pragma unroll
    for (int j = 0; j < 4; j++) {
      int ro = (wc * 64 + j * 16 + l16) * LDT + quad * 8;
      bfh[j] = *reinterpret_cast<bf16x8*>(&Bh[ro]);
      bfl[j] = *reinterpret_cast<bf16x8*>(&Bl[ro]);
    }
#pragma unroll
    for (int i = 0; i < 4; i++)
#pragma unroll
      for (int j = 0; j < 4; j++) {
        acc[i][j] = __builtin_amdgcn_mfma_f32_16x16x32_bf16(afh[i], bfh[j], acc[i][j], 0, 0, 0);
        acc[i][j] = __builtin_amdgcn_mfma_f32_16x16x32_bf16(afh[i], bfl[j], acc[i][j], 0, 0, 0);
        acc[i][j] = __builtin_amdgcn_mfma_f32_16x16x32_bf16(afl[i], bfh[j], acc[i][j], 0, 0, 0);
      }
    __syncthreads();
  }

#pragma unroll
  for (int i = 0; i < 4; i++)
#pragma unroll
    for (int j = 0; j < 4; j++)
#pragma unroll
      for (int r = 0; r < 4; r++) {
        int row = rowA0 + wr * 64 + i * 16 + quad * 4 + r;
        int col = rowB0 + wc * 64 + j * 16 + l16;
        Cg[(long)row * Nn + col] = acc[i][j][r];
      }
}

// ---------------------------------------------------------------------------
// Split-precision fused gate/up, f32 input (fallback path): writes f32.
// ---------------------------------------------------------------------------
__global__ __launch_bounds__(256) void gemm_gu_hl(
    const float* __restrict__ x, const float* __restrict__ Wg,
    const float* __restrict__ Wu, float* __restrict__ Cg, int M, int Nn, int K) {
  constexpr int BM = 128, BN = 64, LDT = 40;
  __shared__ alignas(16) bf16_t Ah[BM * LDT];
  __shared__ alignas(16) bf16_t Al[BM * LDT];
  __shared__ alignas(16) bf16_t B1h[BN * LDT];
  __shared__ alignas(16) bf16_t B1l[BN * LDT];
  __shared__ alignas(16) bf16_t B2h[BN * LDT];
  __shared__ alignas(16) bf16_t B2l[BN * LDT];

  const int tid = threadIdx.x;
  const int wave = tid >> 6, lane = tid & 63;
  const int wr = wave >> 1, wc = wave & 1;
  const int quad = lane >> 4, l16 = lane & 15;
  const int rowA0 = blockIdx.y * BM, rowB0 = blockIdx.x * BN;

  f32x4 ag[4][2] = {}, au[4][2] = {};

  for (int k0 = 0; k0 < K; k0 += 32) {
    for (int c = tid; c < BM * 4; c += 256) {
      int r = c >> 2, kc = c & 3;
      bf16x8 h, l;
      split8(&x[(long)(rowA0 + r) * K + k0 + kc * 8], h, l);
      *reinterpret_cast<bf16x8*>(&Ah[r * LDT + kc * 8]) = h;
      *reinterpret_cast<bf16x8*>(&Al[r * LDT + kc * 8]) = l;
    }
    for (int c = tid; c < BN * 4; c += 256) {
      int r = c >> 2, kc = c & 3;
      long idx = (long)(rowB0 + r) * K + k0 + kc * 8;
      bf16x8 h, l;
      split8(&Wg[idx], h, l);
      *reinterpret_cast<bf16x8*>(&B1h[r * LDT + kc * 8]) = h;
      *reinterpret_cast<bf16x8*>(&B1l[r * LDT + kc * 8]) = l;
      split8(&Wu[idx], h, l);
      *reinterpret_cast<bf16x8*>(&B2h[r * LDT + kc * 8]) = h;
      *reinterpret_cast<bf16x8*>(&B2l[r * LDT + kc * 8]) = l;
    }
    __syncthreads();
    bf16x8 afh[4], afl[4], b1h[2], b1l[2], b2h[2], b2l[2];
#pragma unroll
    for (int i = 0; i < 4; i++) {
      int ro = (wr * 64 + i * 16 + l16) * LDT + quad * 8;
      afh[i] = *reinterpret_cast<bf16x8*>(&Ah[ro]);
      afl[i] = *reinterpret_cast<bf16x8*>(&Al[ro]);
    }
#pragma unroll
    for (int j = 0; j < 2; j++) {
      int ro = (wc * 32 + j * 16 + l16) * LDT + quad * 8;
      b1h[j] = *reinterpret_cast<bf16x8*>(&B1h[ro]);
      b1l[j] = *reinterpret_cast<bf16x8*>(&B1l[ro]);
      b2h[j] = *reinterpret_cast<bf16x8*>(&B2h[ro]);
      b2l[j] = *reinterpret_cast<bf16x8*>(&B2l[ro]);
    }
#pragma unroll
    for (int i = 0; i < 4; i++)
#pragma unroll
      for (int j = 0; j < 2; j++) {
        ag[i][j] = __builtin_amdgcn_mfma_f32_16x16x32_bf16(afh[i], b1h[j], ag[i][j], 0, 0, 0);
        ag[i][j] = __builtin_amdgcn_mfma_f32_16x16x32_bf16(afh[i], b1l[j], ag[i][j], 0, 0, 0);
        ag[i][j] = __builtin_amdgcn_mfma_f32_16x16x32_bf16(afl[i], b1h[j], ag[i][j], 0, 0, 0);
        au[i][j] = __builtin_amdgcn_mfma_f32_16x16x32_bf16(afh[i], b2h[j], au[i][j], 0, 0, 0);
        au[i][j] = __builtin_amdgcn_mfma_f32_16x16x32_bf16(afh[i], b2l[j], au[i][j], 0, 0, 0);
        au[i][j] = __builtin_amdgcn_mfma_f32_16x16x32_bf16(afl[i], b2h[j], au[i][j], 0, 0, 0);
      }
    __syncthreads();
  }

#pragma unroll
  for (int i = 0; i < 4; i++)
#pragma unroll
    for (int j = 0; j < 2; j++)
#pragma unroll
      for (int r = 0; r < 4; r++) {
        int row = rowA0 + wr * 64 + i * 16 + quad * 4 + r;
        int col = rowB0 + wc * 32 + j * 16 + l16;
        Cg[(long)row * Nn + col] = siluf(ag[i][j][r]) * au[i][j][r];
      }
}

// ---------------------------------------------------------------------------
// Fused gate/up from PRE-SPLIT hi/lo bf16 inputs (big-ws path).
// Staging is pure 16B copies; epilogue writes hidden as hi/lo bf16 pair.
// ---------------------------------------------------------------------------
__global__ __launch_bounds__(256) void gemm_gu_b(
    const bf16_t* __restrict__ Ahg, const bf16_t* __restrict__ Alg,
    const bf16_t* __restrict__ B1hg, const bf16_t* __restrict__ B1lg,
    const bf16_t* __restrict__ B2hg, const bf16_t* __restrict__ B2lg,
    bf16_t* __restrict__ Hh, bf16_t* __restrict__ Hl, int M, int Nn, int K) {
  constexpr int BM = 128, BN = 64, LDT = 40;
  __shared__ alignas(16) bf16_t Ah[BM * LDT];
  __shared__ alignas(16) bf16_t Al[BM * LDT];
  __shared__ alignas(16) bf16_t B1h[BN * LDT];
  __shared__ alignas(16) bf16_t B1l[BN * LDT];
  __shared__ alignas(16) bf16_t B2h[BN * LDT];
  __shared__ alignas(16) bf16_t B2l[BN * LDT];

  const int tid = threadIdx.x;
  const int wave = tid >> 6, lane = tid & 63;
  const int wr = wave >> 1, wc = wave & 1;
  const int quad = lane >> 4, l16 = lane & 15;
  const int rowA0 = blockIdx.y * BM, rowB0 = blockIdx.x * BN;

  f32x4 ag[4][2] = {}, au[4][2] = {};

  for (int k0 = 0; k0 < K; k0 += 32) {
    for (int c = tid; c < BM * 4; c += 256) {
      int r = c >> 2, kc = c & 3;
      long idx = (long)(rowA0 + r) * K + k0 + kc * 8;
      int lo = r * LDT + kc * 8;
      *reinterpret_cast<bf16x8*>(&Ah[lo]) = *reinterpret_cast<const bf16x8*>(&Ahg[idx]);
      *reinterpret_cast<bf16x8*>(&Al[lo]) = *reinterpret_cast<const bf16x8*>(&Alg[idx]);
    }
    for (int c = tid; c < BN * 4; c += 256) {
      int r = c >> 2, kc = c & 3;
      long idx = (long)(rowB0 + r) * K + k0 + kc * 8;
      int lo = r * LDT + kc * 8;
      *reinterpret_cast<bf16x8*>(&B1h[lo]) = *reinterpret_cast<const bf16x8*>(&B1hg[idx]);
      *reinterpret_cast<bf16x8*>(&B1l[lo]) = *reinterpret_cast<const bf16x8*>(&B1lg[idx]);
      *reinterpret_cast<bf16x8*>(&B2h[lo]) = *reinterpret_cast<const bf16x8*>(&B2hg[idx]);
      *reinterpret_cast<bf16x8*>(&B2l[lo]) = *reinterpret_cast<const bf16x8*>(&B2lg[idx]);
    }
    __syncthreads();
    bf16x8 afh[4], afl[4], b1h[2], b1l[2], b2h[2], b2l[2];
#pragma unroll
    for (int i = 0; i < 4; i++) {
      int ro = (wr * 64 + i * 16 + l16) * LDT + quad * 8;
      afh[i] = *reinterpret_cast<bf16x8*>(&Ah[ro]);
      afl[i] = *reinterpret_cast<bf16x8*>(&Al[ro]);
    }
#pragma unroll
    for (int j = 0; j < 2; j++) {
      int ro = (wc * 32 + j * 16 + l16) * LDT + quad * 8;
      b1h[j] = *reinterpret_cast<bf16x8*>(&B1h[ro]);
      b1l[j] = *reinterpret_cast<bf16x8*>(&B1l[ro]);
      b2h[j] = *reinterpret_cast<bf16x8*>(&B2h[ro]);
      b2l[j] = *reinterpret_cast<bf16x8*>(&B2l[ro]);
    }
#pragma unroll
    for (int i = 0; i < 4; i++)
#pragma unroll
      for (int j = 0; j < 2; j++) {
        ag[i][j] = __builtin_amdgcn_mfma_f32_16x16x32_bf16(afh[i], b1h[j], ag[i][j], 0, 0, 0);
        ag[i][j] = __builtin_amdgcn_mfma_f32_16x16x32_bf16(afh[i], b1l[j], ag[i][j], 0, 0, 0);
        ag[i][j] = __builtin_amdgcn_mfma_f32_16x16x32_bf16(afl[i], b1h[j], ag[i][j], 0, 0, 0);
        au[i][j] = __builtin_amdgcn_mfma_f32_16x16x32_bf16(afh[i], b2h[j], au[i][j], 0, 0, 0);
        au[i][j] = __builtin_amdgcn_mfma_f32_16x16x32_bf16(afh[i], b2l[j], au[i][j], 0, 0, 0);
        au[i][j] = __builtin_amdgcn_mfma_f32_16x16x32_bf16(afl[i], b2h[j], au[i][j], 0, 0, 0);
      }
    __syncthreads();
  }

#pragma unroll
  for (int i = 0; i < 4; i++)
#pragma unroll
    for (int j = 0; j < 2; j++)
#pragma unroll
      for (int r = 0; r < 4; r++) {
        int row = rowA0 + wr * 64 + i * 16 + quad * 4 + r;
        int col = rowB0 + wc * 32 + j * 16 + l16;
        long o = (long)row * Nn + col;
        float v = siluf(ag[i][j][r]) * au[i][j][r];
        bf16_t hh = f2b(v);
        Hh[o] = hh;
        Hl[o] = f2b(v - b2f(hh));
      }
}

// ---------------------------------------------------------------------------
// Router (R8 version: no global atomics, per-block partials).
// ---------------------------------------------------------------------------
__global__ __launch_bounds__(256) void router_kernel(
    const float* __restrict__ x, const float* __restrict__ Wgr,
    const float* __restrict__ Wer, int* __restrict__ eidx,
    float* __restrict__ fw, float* __restrict__ wsum,
    float* __restrict__ lpart) {
  __shared__ float part[4][12];
  const int wv = threadIdx.x >> 6;
  const int lane = threadIdx.x & 63;
  const int token = blockIdx.x * 4 + wv;
  if (lane < 12) part[wv][lane] = 0.f;
  const float* xp = x + (long)token * D;
  float xr[16];
#pragma unroll
  for (int i = 0; i < 16; i++) xr[i] = xp[lane + i * 64];
  float dots[6];
#pragma unroll
  for (int w = 0; w < 6; w++) {
    const float* wp = (w < 2) ? (Wgr + (long)w * D) : (Wer + (long)(w - 2) * D);
    float s = 0.f;
#pragma unroll
    for (int i = 0; i < 16; i++) s += xr[i] * wp[lane + i * 64];
#pragma unroll
    for (int off = 32; off; off >>= 1) s += __shfl_xor(s, off);
    dots[w] = s;
  }
  if (lane == 0) {
    float gl0 = dots[0], gl1 = dots[1];
    float mg = fmaxf(gl0, gl1);
    float e0 = expf(gl0 - mg), e1 = expf(gl1 - mg);
    float inv = 1.f / (e0 + e1);
    float gp0 = e0 * inv, gp1 = e1 * inv;
    int gi = (gp1 > gp0) ? 1 : 0;
    float gw = gi ? gp1 : gp0;
    float el[4] = {dots[2], dots[3], dots[4], dots[5]};
    float me = fmaxf(fmaxf(el[0], el[1]), fmaxf(el[2], el[3]));
    float ep[4], es = 0.f;
#pragma unroll
    for (int j = 0; j < 4; j++) { ep[j] = expf(el[j] - me); es += ep[j]; }
    float inve = 1.f / es;
#pragma unroll
    for (int j = 0; j < 4; j++) ep[j] *= inve;
    int i1 = 0;
    for (int j = 1; j < 4; j++) if (ep[j] > ep[i1]) i1 = j;
    int i2 = (i1 == 0) ? 1 : 0;
    for (int j = 0; j < 4; j++) if (j != i1 && j != i2 && ep[j] > ep[i2]) i2 = j;
    float l1 = ep[i1], l2 = ep[i2];
    float ils = 1.f / (l1 + l2 + 1e-7f);
    float f1 = gw * l1 * ils, f2 = gw * l2 * ils;
    eidx[token * 2] = gi * 4 + i1;
    eidx[token * 2 + 1] = gi * 4 + i2;
    fw[token * 2] = f1;
    fw[token * 2 + 1] = f2;
    wsum[token] = f1 + f2;
    part[wv][gi * 4 + i1] = f1;
    part[wv][gi * 4 + i2] = f2;
    part[wv][8] = gl0 * gl0 + gl1 * gl1;
    part[wv][9] = el[0] * el[0] + el[1] * el[1] + el[2] * el[2] + el[3] * el[3];
  }
  __syncthreads();
  if (threadIdx.x < 12) {
    lpart[(long)blockIdx.x * 12 + threadIdx.x] =
        part[0][threadIdx.x] + part[1][threadIdx.x] +
        part[2][threadIdx.x] + part[3][threadIdx.x];
  }
}

// ---------------------------------------------------------------------------
// Row LayerNorm over A=128 (bf16 in ws, f32 g/b, bf16 out).
// ---------------------------------------------------------------------------
__global__ __launch_bounds__(256) void ln_rows(
    const bf16_t* __restrict__ in, const float* __restrict__ g,
    const float* __restrict__ b, bf16_t* __restrict__ out) {
  const int row = blockIdx.x * 4 + (threadIdx.x >> 6);
  const int lane = threadIdx.x & 63;
  const bf16_t* p = in + (long)row * A;
  float x0 = b2f(p[lane]), x1 = b2f(p[lane + 64]);
  float s = x0 + x1;
#pragma unroll
  for (int off = 32; off; off >>= 1) s += __shfl_xor(s, off);
  float mean = s * (1.f / 128.f);
  float d0 = x0 - mean, d1 = x1 - mean;
  float q = d0 * d0 + d1 * d1;
#pragma unroll
  for (int off = 32; off; off >>= 1) q += __shfl_xor(q, off);
  float r = rsqrtf(q * (1.f / 128.f) + 1e-5f);
  bf16_t* po = out + (long)row * A;
  po[lane] = f2b(d0 * r * g[lane] + b[lane]);
  po[lane + 64] = f2b(d1 * r * g[lane + 64] + b[lane + 64]);
}

// ---------------------------------------------------------------------------
// Transpose [z,R,C] -> [z,C,R], bf16 out; input f32 (isf=1) or bf16.
// ---------------------------------------------------------------------------
__global__ __launch_bounds__(256) void transpose2d(
    const void* __restrict__ in, bf16_t* __restrict__ out, int R, int C, int isf) {
  __shared__ bf16_t t[32][33];
  const long zb = blockIdx.z;
  const long ib = zb * (long)R * C;
  bf16_t* op = out + zb * (long)R * C;
  const int r0 = blockIdx.y * 32, c0 = blockIdx.x * 32;
  const int tx = threadIdx.x & 31, ty = threadIdx.x >> 5;
#pragma unroll
  for (int i = 0; i < 4; i++) {
    long idx = ib + (long)(r0 + ty + i * 8) * C + c0 + tx;
    t[ty + i * 8][tx] = isf ? f2b(reinterpret_cast<const float*>(in)[idx])
                            : reinterpret_cast<const bf16_t*>(in)[idx];
  }
  __syncthreads();
#pragma unroll
  for (int i = 0; i < 4; i++) op[(long)(c0 + ty + i * 8) * R + r0 + tx] = t[tx][ty + i * 8];
}

// ---------------------------------------------------------------------------
// Expert branch: coalesced via pre-transposed WeaT[e][a][c] (bf16).
// ---------------------------------------------------------------------------
__global__ __launch_bounds__(128) void expert_adapt(
    const bf16_t* __restrict__ h0, const bf16_t* __restrict__ WeaT,
    const float* __restrict__ ln_eg, const float* __restrict__ ln_eb,
    const int* __restrict__ eidx, const float* __restrict__ fw,
    bf16_t* __restrict__ hw) {
  const int n = blockIdx.x;
  const int c = threadIdx.x;
  __shared__ float h0s[128];
  __shared__ float red[4];
  h0s[c] = b2f(h0[(long)n * A + c]);
  __syncthreads();
  float out = 0.f;
  for (int k = 0; k < 2; k++) {
    int e = eidx[n * 2 + k];
    e = min(max(e, 0), E - 1);
    float w = fw[n * 2 + k];
    const bf16_t* Wc = WeaT + (long)e * A * A + c;  // column c, stride A over a
    float t = 0.f;
#pragma unroll 8
    for (int a = 0; a < 128; a++) t += b2f(Wc[(long)a * A]) * h0s[a];
    float s = t, q = t * t;
#pragma unroll
    for (int off = 32; off; off >>= 1) { s += __shfl_xor(s, off); q += __shfl_xor(q, off); }
    if ((c & 63) == 0) { red[(c >> 6) * 2] = s; red[(c >> 6) * 2 + 1] = q; }
    __syncthreads();
    float Sx = red[0] + red[2], Qx = red[1] + red[3];
    float mean = Sx * (1.f / 128.f);
    float var = Qx * (1.f / 128.f) - mean * mean;
    float r = rsqrtf(var + 1e-5f);
    out += w * ((t - mean) * r * ln_eg[e * A + c] + ln_eb[e * A + c]);
    __syncthreads();
  }
  hw[(long)n * A + c] = f2b(out);
}

// ---------------------------------------------------------------------------
// Loss finalize: reduce 2048 per-block 12-float partials, then scalar.
// ---------------------------------------------------------------------------
__global__ __launch_bounds__(256) void finalize_loss(
    const float* __restrict__ lpart, int nblk, float* __restrict__ outv) {
  float acc[10] = {};
  for (int b = threadIdx.x; b < nblk; b += 256) {
    const float* p = lpart + (long)b * 12;
#pragma unroll
    for (int c = 0; c < 10; c++) acc[c] += p[c];
  }
  __shared__ float red[10][4];
  const int lane = threadIdx.x & 63, wv = threadIdx.x >> 6;
#pragma unroll
  for (int c = 0; c < 10; c++) {
    float s = acc[c];
#pragma unroll
    for (int off = 32; off; off >>= 1) s += __shfl_xor(s, off);
    if (lane == 0) red[c][wv] = s;
  }
  __syncthreads();
  if (threadIdx.x == 0) {
    float loss[10];
#pragma unroll
    for (int c = 0; c < 10; c++)
      loss[c] = red[c][0] + red[c][1] + red[c][2] + red[c][3];
    float tl = 0.f;
    for (int e = 0; e < 8; e++) tl += loss[e];
    float target = tl / 8.f;
    float mse = 0.f;
    for (int e = 0; e < 8; e++) { float d = loss[e] - target; mse += d * d; }
    mse *= (1.f / 8.f);
    outv[0] = 0.001f * (mse + loss[8] / (float)(N * 2) + loss[9] / (float)(N * 4));
  }
}

// ---------------------------------------------------------------------------
extern "C" void kernel_launch(void* const* d_in, const int* in_sizes, int n_in,
                              void* d_out, int out_size, void* d_ws, size_t ws_size,
                              hipStream_t stream) {
  const float* x = (const float*)d_in[0];
  const float* Wu = (const float*)d_in[1];
  const float* Wg = (const float*)d_in[2];
  const float* Wd = (const float*)d_in[3];
  const float* Wpre = (const float*)d_in[4];
  const float* Wpost = (const float*)d_in[5];
  const float* ln_g = (const float*)d_in[6];
  const float* ln_b = (const float*)d_in[7];
  const float* Wap = (const float*)d_in[8];
  const float* Wea = (const float*)d_in[9];
  const float* ln_eg = (const float*)d_in[10];
  const float* ln_eb = (const float*)d_in[11];
  const float* Wep = (const float*)d_in[12];
  const float* Wop = (const float*)d_in[13];
  const float* Wgr = (const float*)d_in[14];
  const float* Wer = (const float*)d_in[15];
  float* out = (float*)d_out;

  char* ws = (char*)d_ws;
  size_t off = 0;
  auto alloc = [&](size_t bytes) { char* p = ws + off; off += (bytes + 255) & ~size_t(255); return p; };
  // Common allocations (~20.2 MB)
  float* lpart = (float*)alloc((size_t)(N / 4) * 12 * 4);
  float* wsum = (float*)alloc((size_t)N * 4);
  float* fwb = (float*)alloc((size_t)N * 2 * 4);
  int* eidx = (int*)alloc((size_t)N * 2 * 4);
  bf16_t* Mb = (bf16_t*)alloc((size_t)D * A * 2);
  bf16_t* WepT = (bf16_t*)alloc((size_t)H * A * 2);
  bf16_t* hwb = (bf16_t*)alloc((size_t)N * A * 2);
  bf16_t* h0b = (bf16_t*)alloc((size_t)N * A * 2);
  bf16_t* aib = (bf16_t*)alloc((size_t)N * A * 2);
  bf16_t* scrA = (bf16_t*)alloc((size_t)N * A * 2);
  bf16_t* scrB = (bf16_t*)alloc((size_t)N * A * 2);
  bf16_t* awb = (bf16_t*)alloc((size_t)S * S * 2);
  bf16_t* WeaT = (bf16_t*)alloc((size_t)E * A * A * 2);
  bf16_t* aopre = scrA;
  bf16_t* aiT = scrA;
  bf16_t* aob = scrB;
  bf16_t* adpre = scrB;

  // Big path: pre-split hi/lo buffers (+120 MB; total ~139.3 MiB).
  const bool big = ws_size >= ((size_t)140 << 20);
  float* hiddenF = nullptr;
  bf16_t *xh = nullptr, *xl = nullptr;
  bf16_t *Wgh = nullptr, *Wgl = nullptr, *Wuh = nullptr, *Wul = nullptr;
  bf16_t *Wdh = nullptr, *Wdl = nullptr, *Hh = nullptr, *Hl = nullptr;
  if (big) {
    xh = (bf16_t*)alloc((size_t)N * D * 2);
    xl = (bf16_t*)alloc((size_t)N * D * 2);
    Wgh = (bf16_t*)alloc((size_t)H * D * 2);
    Wgl = (bf16_t*)alloc((size_t)H * D * 2);
    Wuh = (bf16_t*)alloc((size_t)H * D * 2);
    Wul = (bf16_t*)alloc((size_t)H * D * 2);
    Wdh = (bf16_t*)alloc((size_t)D * H * 2);
    Wdl = (bf16_t*)alloc((size_t)D * H * 2);
    Hh = (bf16_t*)alloc((size_t)N * H * 2);
    Hl = (bf16_t*)alloc((size_t)N * H * 2);
  } else {
    hiddenF = (float*)alloc((size_t)N * H * 4);
  }
  (void)ws_size; (void)in_sizes; (void)n_in; (void)out_size;

  const dim3 blk(256);

  router_kernel<<<dim3(N / 4), blk, 0, stream>>>(x, Wgr, Wer, eidx, fwb, wsum, lpart);
  // WeaT[e][a][c] = Wea[e][c][a] (f32 -> bf16), both paths
  transpose2d<<<dim3(A / 32, A / 32, E), blk, 0, stream>>>(Wea, WeaT, A, A, 1);

  if (big) {
    split_pass<<<dim3(2048), blk, 0, stream>>>(x, xh, xl, (long)N * D / 8);
    split_pass<<<dim3(1024), blk, 0, stream>>>(Wg, Wgh, Wgl, (long)H * D / 8);
    split_pass<<<dim3(1024), blk, 0, stream>>>(Wu, Wuh, Wul, (long)H * D / 8);
    split_pass<<<dim3(1024), blk, 0, stream>>>(Wd, Wdh, Wdl, (long)D * H / 8);
    // hidden (as Hh/Hl) = silu(x@Wg^T)*(x@Wu^T), split-precision [N,H] K=D
    gemm_gu_b<<<dim3(H / 64, N / 128), blk, 0, stream>>>(
        xh, xl, Wgh, Wgl, Wuh, Wul, Hh, Hl, N, H, D);
    // h0 = x@Wpre^T  [N,A] K=D  (A operand = xh, bit-identical to ld8f(x))
    gemm_nt_b<32, 32, 0><<<dim3(A / 64, N / 64), blk, 0, stream>>>(
        xh, Wpre, h0b, nullptr, N, A, D, nullptr, 0, 1);
    ln_rows<<<dim3(N / 4), blk, 0, stream>>>(h0b, ln_g, ln_b, aib);
    // ao_pre = hidden@Wpost^T  [N,A] K=H  (A operand = Hh, == ld8f(hiddenF))
    gemm_nt_b<32, 32, 0><<<dim3(A / 64, N / 64), blk, 0, stream>>>(
        Hh, Wpost, aopre, nullptr, N, A, H, nullptr, 0, 1);
    ln_rows<<<dim3(N / 4), blk, 0, stream>>>(aopre, ln_g, ln_b, aob);
    transpose2d<<<dim3(A / 32, S / 32, Bb), blk, 0, stream>>>(aib, aiT, S, A, 0);
    for (int b = 0; b < Bb; b++) {
      const bf16_t* ai_b = aib + (size_t)b * S * A;
      const bf16_t* ao_b = aob + (size_t)b * S * A;
      const bf16_t* aiT_b = aiT + (size_t)b * A * S;
      bf16_t* adpre_b = adpre + (size_t)b * S * A;
      gemm_nt_b<64, 64, 1><<<dim3(S / 128, S / 128), blk, 0, stream>>>(
          ai_b, ao_b, awb, nullptr, S, S, A, nullptr, 0, 0);
      gemm_nt_b<32, 32, 0><<<dim3(A / 64, S / 64), blk, 0, stream>>>(
          awb, aiT_b, adpre_b, nullptr, S, A, S, nullptr, 0, 0);
    }
    // hidden += 0.1 * adpre@Wap^T  (hi/lo RMW: reconstruct, add, re-split)
    gemm_nt_b<64, 64, 4><<<dim3(H / 128, N / 128), blk, 0, stream>>>(
        adpre, Wap, Hh, Hl, N, H, A, nullptr, 0, 1);
    // out = hidden@Wd^T  split-precision from pre-split operands
    gemm_dn_b<<<dim3(D / 128, N / 128), blk, 0, stream>>>(
        Hh, Hl, Wdh, Wdl, out, N, D, H);
  } else {
    gemm_gu_hl<<<dim3(H / 64, N / 128), blk, 0, stream>>>(x, Wg, Wu, hiddenF, N, H, D);
    gemm_nt_b<32, 32, 0><<<dim3(A / 64, N / 64), blk, 0, stream>>>(
        x, Wpre, h0b, nullptr, N, A, D, nullptr, 1, 1);
    ln_rows<<<dim3(N / 4), blk, 0, stream>>>(h0b, ln_g, ln_b, aib);
    gemm_nt_b<32, 32, 0><<<dim3(A / 64, N / 64), blk, 0, stream>>>(
        hiddenF, Wpost, aopre, nullptr, N, A, H, nullptr, 1, 1);
    ln_rows<<<dim3(N / 4), blk, 0, stream>>>(aopre, ln_g, ln_b, aob);
    transpose2d<<<dim3(A / 32, S / 32, Bb), blk, 0, stream>>>(aib, aiT, S, A, 0);
    for (int b = 0; b < Bb; b++) {
      const bf16_t* ai_b = aib + (size_t)b * S * A;
      const bf16_t* ao_b = aob + (size_t)b * S * A;
      const bf16_t* aiT_b = aiT + (size_t)b * A * S;
      bf16_t* adpre_b = adpre + (size_t)b * S * A;
      gemm_nt_b<64, 64, 1><<<dim3(S / 128, S / 128), blk, 0, stream>>>(
          ai_b, ao_b, awb, nullptr, S, S, A, nullptr, 0, 0);
      gemm_nt_b<32, 32, 0><<<dim3(A / 64, S / 64), blk, 0, stream>>>(
          awb, aiT_b, adpre_b, nullptr, S, A, S, nullptr, 0, 0);
    }
    gemm_nt_b<64, 64, 2><<<dim3(H / 128, N / 128), blk, 0, stream>>>(
        adpre, Wap, hiddenF, nullptr, N, H, A, nullptr, 0, 1);
    gemm_dn_hl<<<dim3(D / 128, N / 128), blk, 0, stream>>>(hiddenF, Wd, out, N, D, H);
  }

  // Common tail
  transpose2d<<<dim3(A / 32, H / 32, 1), blk, 0, stream>>>(Wep, WepT, H, A, 1);
  gemm_nt_b<32, 32, 0><<<dim3(A / 64, D / 64), blk, 0, stream>>>(
      Wop, WepT, Mb, nullptr, D, A, H, nullptr, 1, 0);
  expert_adapt<<<dim3(N), dim3(128), 0, stream>>>(h0b, WeaT, ln_eg, ln_eb, eidx, fwb, hwb);
  gemm_nt_b<64, 64, 3><<<dim3(D / 128, N / 128), blk, 0, stream>>>(
      hwb, Mb, out, nullptr, N, D, A, wsum, 0, 0);
  finalize_loss<<<dim3(1), blk, 0, stream>>>(lpart, N / 4, out + (size_t)N * D);
}

// Round 4
// 861.320 us; speedup vs baseline: 1.7628x; 1.1419x over previous
//
#include <hip/hip_runtime.h>
#include <math.h>

// ---------------------------------------------------------------------------
// MoE layer, round 11: attack the serialized small-kernel tail.
// R10 profile: gemm_gu_b 232us = 888 TF MFMA = at the 2-barrier structural
// ceiling (m97: 874-912); T2/pipelining proven null at 2-phase -> gu/dn done.
// Gap analysis: ~550us of accounted kernel work vs 983 total -> latency-bound
// small dispatches. Changes:
//  1. aw+adpre fused flash-style (no softmax -> no rescale), identical K-order
//     and P rounding -> removes 8 launches + awb + 32MB traffic.
//  2. Mb split-K x8 (was 32 blocks x 64 ksteps exposed-latency).
//  3. h0/aopre at WM=16 (512 blocks, 8 waves/CU for TLP).
//  4. merged weight split pass.
// B=4, S=2048, D=1024, H=2048, A=128, E=8, N=8192.
// ---------------------------------------------------------------------------

typedef __bf16 bf16_t;
typedef __attribute__((ext_vector_type(8))) __bf16 bf16x8;
typedef __attribute__((ext_vector_type(4))) float f32x4;

__device__ __forceinline__ float b2f(bf16_t v) { return (float)v; }
__device__ __forceinline__ bf16_t f2b(float v) { return (bf16_t)v; }
__device__ __forceinline__ float siluf(float v) { return v / (1.f + expf(-v)); }

static constexpr int Bb = 4, S = 2048, D = 1024, H = 2048, A = 128, E = 8;
static constexpr int N = Bb * S;

// 8 consecutive f32 -> bf16 (plain round)
__device__ __forceinline__ bf16x8 ld8f(const float* p) {
  float4 a = *reinterpret_cast<const float4*>(p);
  float4 b = *reinterpret_cast<const float4*>(p + 4);
  bf16x8 r;
  r[0] = f2b(a.x); r[1] = f2b(a.y); r[2] = f2b(a.z); r[3] = f2b(a.w);
  r[4] = f2b(b.x); r[5] = f2b(b.y); r[6] = f2b(b.z); r[7] = f2b(b.w);
  return r;
}
// 8 consecutive f32 -> hi/lo bf16 split
__device__ __forceinline__ void split8(const float* p, bf16x8& h, bf16x8& l) {
  float4 a = *reinterpret_cast<const float4*>(p);
  float4 b = *reinterpret_cast<const float4*>(p + 4);
  float v[8] = {a.x, a.y, a.z, a.w, b.x, b.y, b.z, b.w};
#pragma unroll
  for (int j = 0; j < 8; j++) {
    bf16_t hh = f2b(v[j]);
    h[j] = hh;
    l[j] = f2b(v[j] - b2f(hh));
  }
}
// mixed loader for plain-bf16 GEMM staging
__device__ __forceinline__ bf16x8 ld8(const void* p, long i, int isf) {
  if (isf) return ld8f(reinterpret_cast<const float*>(p) + i);
  return *reinterpret_cast<const bf16x8*>(reinterpret_cast<const bf16_t*>(p) + i);
}

// ---------------------------------------------------------------------------
// Elementwise f32 -> hi/lo bf16 split pass (grid-stride over groups of 8).
// ---------------------------------------------------------------------------
__global__ __launch_bounds__(256) void split_pass(
    const float* __restrict__ in, bf16_t* __restrict__ hi,
    bf16_t* __restrict__ lo, long n8) {
  long stride = (long)gridDim.x * blockDim.x;
  for (long i = (long)blockIdx.x * blockDim.x + threadIdx.x; i < n8; i += stride) {
    bf16x8 h, l;
    split8(in + i * 8, h, l);
    reinterpret_cast<bf16x8*>(hi)[i] = h;
    reinterpret_cast<bf16x8*>(lo)[i] = l;
  }
}

// Three equally-sized weight splits in one launch (Wg, Wu, Wd: H*D each).
__global__ __launch_bounds__(256) void split3_pass(
    const float* __restrict__ s0, bf16_t* __restrict__ h0, bf16_t* __restrict__ l0,
    const float* __restrict__ s1, bf16_t* __restrict__ h1, bf16_t* __restrict__ l1,
    const float* __restrict__ s2, bf16_t* __restrict__ h2, bf16_t* __restrict__ l2,
    long n8each) {
  long stride = (long)gridDim.x * blockDim.x;
  for (long i = (long)blockIdx.x * blockDim.x + threadIdx.x; i < 3 * n8each; i += stride) {
    int which = (int)(i / n8each);
    long li = i - (long)which * n8each;
    const float* src = (which == 0) ? s0 : (which == 1) ? s1 : s2;
    bf16_t* hh = (which == 0) ? h0 : (which == 1) ? h1 : h2;
    bf16_t* ll = (which == 0) ? l0 : (which == 1) ? l1 : l2;
    bf16x8 h, l;
    split8(src + li * 8, h, l);
    reinterpret_cast<bf16x8*>(hh)[li] = h;
    reinterpret_cast<bf16x8*>(ll)[li] = l;
  }
}

// ---------------------------------------------------------------------------
// Plain-bf16 NT GEMM (verified layout).
// MODE: 0 bf16 store; 1 silu(clip(v,-5,5)) bf16; 2 f32 RMW C += 0.1*v;
//       3 f32 RMW C = C*aux[row] + 0.1*v;
//       4 hi/lo bf16 RMW: s = (Ch+Cl) + 0.1*v; Ch,Cl = split(s)
// ---------------------------------------------------------------------------
template <int WM, int WN, int MODE>
__global__ __launch_bounds__(256) void gemm_nt_b(
    const void* __restrict__ Ag, const void* __restrict__ Bg,
    void* __restrict__ Cv, void* __restrict__ Cv2, int M, int Nn, int K,
    const float* __restrict__ aux, int aF, int bF) {
  constexpr int BM = 2 * WM, BN = 2 * WN, AM = WM / 16, AN = WN / 16;
  constexpr int LDT = 40;
  __shared__ alignas(16) bf16_t As[BM * LDT];
  __shared__ alignas(16) bf16_t Bs[BN * LDT];

  const int tid = threadIdx.x;
  const int wave = tid >> 6, lane = tid & 63;
  const int wr = wave >> 1, wc = wave & 1;
  const int quad = lane >> 4, l16 = lane & 15;
  const int rowA0 = blockIdx.y * BM, rowB0 = blockIdx.x * BN;

  f32x4 acc[AM][AN] = {};

  for (int k0 = 0; k0 < K; k0 += 32) {
    for (int c = tid; c < BM * 4; c += 256) {
      int r = c >> 2, kc = c & 3;
      *reinterpret_cast<bf16x8*>(&As[r * LDT + kc * 8]) =
          ld8(Ag, (long)(rowA0 + r) * K + k0 + kc * 8, aF);
    }
    for (int c = tid; c < BN * 4; c += 256) {
      int r = c >> 2, kc = c & 3;
      *reinterpret_cast<bf16x8*>(&Bs[r * LDT + kc * 8]) =
          ld8(Bg, (long)(rowB0 + r) * K + k0 + kc * 8, bF);
    }
    __syncthreads();
    bf16x8 af[AM], bfv[AN];
#pragma unroll
    for (int i = 0; i < AM; i++)
      af[i] = *reinterpret_cast<bf16x8*>(&As[(wr * WM + i * 16 + l16) * LDT + quad * 8]);
#pragma unroll
    for (int j = 0; j < AN; j++)
      bfv[j] = *reinterpret_cast<bf16x8*>(&Bs[(wc * WN + j * 16 + l16) * LDT + quad * 8]);
#pragma unroll
    for (int i = 0; i < AM; i++)
#pragma unroll
      for (int j = 0; j < AN; j++)
        acc[i][j] = __builtin_amdgcn_mfma_f32_16x16x32_bf16(af[i], bfv[j], acc[i][j], 0, 0, 0);
    __syncthreads();
  }

  // C/D: col = lane&15, row = quad*4 + reg
#pragma unroll
  for (int i = 0; i < AM; i++)
#pragma unroll
    for (int j = 0; j < AN; j++)
#pragma unroll
      for (int r = 0; r < 4; r++) {
        int row = rowA0 + wr * WM + i * 16 + quad * 4 + r;
        int col = rowB0 + wc * WN + j * 16 + l16;
        long o = (long)row * Nn + col;
        float v = acc[i][j][r];
        if constexpr (MODE == 0) {
          reinterpret_cast<bf16_t*>(Cv)[o] = f2b(v);
        } else if constexpr (MODE == 1) {
          v = fminf(fmaxf(v, -5.f), 5.f);
          reinterpret_cast<bf16_t*>(Cv)[o] = f2b(siluf(v));
        } else if constexpr (MODE == 2) {
          float* C = reinterpret_cast<float*>(Cv);
          C[o] = C[o] + 0.1f * v;
        } else if constexpr (MODE == 3) {
          float* C = reinterpret_cast<float*>(Cv);
          C[o] = C[o] * aux[row] + 0.1f * v;
        } else {
          bf16_t* Ch = reinterpret_cast<bf16_t*>(Cv);
          bf16_t* Cl = reinterpret_cast<bf16_t*>(Cv2);
          float s = b2f(Ch[o]) + b2f(Cl[o]) + 0.1f * v;
          bf16_t hh = f2b(s);
          Ch[o] = hh;
          Cl[o] = f2b(s - b2f(hh));
        }
      }
}

// ---------------------------------------------------------------------------
// Fused adapt attention (per batch): adpre = silu(clip(ai@ao^T)) @ ai
// Flash-style, no softmax -> no rescale. QBLK=64 q-rows per block, loop over
// 32 t-tiles of 64. P rounded to bf16 exactly like the old awb buffer; the
// PV accumulation K-order matches the old adpre GEMM (t ascending, K=32
// chunks) -> numerics preserved.
// grid: (S/64, Bb). 256 threads = 4 waves (2x2).
// ---------------------------------------------------------------------------
__global__ __launch_bounds__(256) void fused_adapt(
    const bf16_t* __restrict__ aib, const bf16_t* __restrict__ aob,
    const bf16_t* __restrict__ aiT, bf16_t* __restrict__ adpre) {
  constexpr int LDQ = 136;  // 128 + 8 pad, rows 16B-aligned (272B)
  constexpr int LDP = 72;   // 64 + 8 pad (144B)
  __shared__ alignas(16) bf16_t Qs[64 * LDQ];
  __shared__ alignas(16) bf16_t Os[64 * LDQ];
  __shared__ alignas(16) bf16_t Ps[64 * LDP];
  __shared__ alignas(16) bf16_t Vs[128 * LDP];

  const int tid = threadIdx.x;
  const int wave = tid >> 6, lane = tid & 63;
  const int wr = wave >> 1, wc = wave & 1;
  const int quad = lane >> 4, l16 = lane & 15;
  const int b = blockIdx.y;
  const int q0 = blockIdx.x * 64;

  // stage Q tile [64][128] once
  for (int c = tid; c < 1024; c += 256) {
    int r = c >> 4, cc = c & 15;
    *reinterpret_cast<bf16x8*>(&Qs[r * LDQ + cc * 8]) =
        *reinterpret_cast<const bf16x8*>(&aib[((long)b * S + q0 + r) * A + cc * 8]);
  }

  f32x4 o[2][4] = {};  // persistent PV accumulator: 32q x 64a per wave

  for (int tt = 0; tt < S / 64; tt++) {
    const int t0 = tt * 64;
    __syncthreads();  // prev PV reads done (and Qs visible at tt=0)
    // stage ao tile [64][128] and aiT tile [128][64]
    for (int c = tid; c < 1024; c += 256) {
      int r = c >> 4, cc = c & 15;
      *reinterpret_cast<bf16x8*>(&Os[r * LDQ + cc * 8]) =
          *reinterpret_cast<const bf16x8*>(&aob[((long)b * S + t0 + r) * A + cc * 8]);
    }
    for (int c = tid; c < 1024; c += 256) {
      int r = c >> 3, cc = c & 7;
      *reinterpret_cast<bf16x8*>(&Vs[r * LDP + cc * 8]) =
          *reinterpret_cast<const bf16x8*>(&aiT[((long)b * A + r) * S + t0 + cc * 8]);
    }
    __syncthreads();
    // QK^T: P[64q, 64t], wave covers 32q x 32t
    f32x4 p[2][2] = {};
#pragma unroll
    for (int ks = 0; ks < 4; ks++) {
      bf16x8 af[2], bfv[2];
#pragma unroll
      for (int i = 0; i < 2; i++)
        af[i] = *reinterpret_cast<bf16x8*>(&Qs[(wr * 32 + i * 16 + l16) * LDQ + ks * 32 + quad * 8]);
#pragma unroll
      for (int j = 0; j < 2; j++)
        bfv[j] = *reinterpret_cast<bf16x8*>(&Os[(wc * 32 + j * 16 + l16) * LDQ + ks * 32 + quad * 8]);
#pragma unroll
      for (int i = 0; i < 2; i++)
#pragma unroll
        for (int j = 0; j < 2; j++)
          p[i][j] = __builtin_amdgcn_mfma_f32_16x16x32_bf16(af[i], bfv[j], p[i][j], 0, 0, 0);
    }
    // silu(clip) -> bf16 -> Ps
#pragma unroll
    for (int i = 0; i < 2; i++)
#pragma unroll
      for (int j = 0; j < 2; j++)
#pragma unroll
        for (int r = 0; r < 4; r++) {
          int row = wr * 32 + i * 16 + quad * 4 + r;
          int col = wc * 32 + j * 16 + l16;
          float v = fminf(fmaxf(p[i][j][r], -5.f), 5.f);
          Ps[row * LDP + col] = f2b(siluf(v));
        }
    __syncthreads();
    // PV: adpre[64q, 128a] += P[64q,64t] @ aiT[128a,64t]^T; wave: 32q x 64a
#pragma unroll
    for (int ks = 0; ks < 2; ks++) {
      bf16x8 paf[2], vbf[4];
#pragma unroll
      for (int i = 0; i < 2; i++)
        paf[i] = *reinterpret_cast<bf16x8*>(&Ps[(wr * 32 + i * 16 + l16) * LDP + ks * 32 + quad * 8]);
#pragma unroll
      for (int j = 0; j < 4; j++)
        vbf[j] = *reinterpret_cast<bf16x8*>(&Vs[(wc * 64 + j * 16 + l16) * LDP + ks * 32 + quad * 8]);
#pragma unroll
      for (int i = 0; i < 2; i++)
#pragma unroll
        for (int j = 0; j < 4; j++)
          o[i][j] = __builtin_amdgcn_mfma_f32_16x16x32_bf16(paf[i], vbf[j], o[i][j], 0, 0, 0);
    }
  }

#pragma unroll
  for (int i = 0; i < 2; i++)
#pragma unroll
    for (int j = 0; j < 4; j++)
#pragma unroll
      for (int r = 0; r < 4; r++) {
        int row = q0 + wr * 32 + i * 16 + quad * 4 + r;
        int col = wc * 64 + j * 16 + l16;
        adpre[((long)b * S + row) * A + col] = f2b(o[i][j][r]);
      }
}

// ---------------------------------------------------------------------------
// Mb = Wop @ WepT^T, split-K x8 into f32 partials (was 32-block latency-bound).
// grid (Nn/64, M/64, 8); A = Wop f32 (ld8f), B = WepT bf16.
// ---------------------------------------------------------------------------
__global__ __launch_bounds__(256) void gemm_mb_splitk(
    const float* __restrict__ Ag, const bf16_t* __restrict__ Bg,
    float* __restrict__ Mp, int M, int Nn, int K) {
  constexpr int BM = 64, BN = 64, LDT = 40;
  __shared__ alignas(16) bf16_t As[BM * LDT];
  __shared__ alignas(16) bf16_t Bs[BN * LDT];
  const int tid = threadIdx.x;
  const int wave = tid >> 6, lane = tid & 63;
  const int wr = wave >> 1, wc = wave & 1;
  const int quad = lane >> 4, l16 = lane & 15;
  const int rowA0 = blockIdx.y * BM, rowB0 = blockIdx.x * BN;
  const int kz = blockIdx.z;
  const int ks0 = kz * (K / 8), ks1 = ks0 + K / 8;

  f32x4 acc[2][2] = {};
  for (int k0 = ks0; k0 < ks1; k0 += 32) {
    for (int c = tid; c < BM * 4; c += 256) {
      int r = c >> 2, kc = c & 3;
      *reinterpret_cast<bf16x8*>(&As[r * LDT + kc * 8]) =
          ld8f(Ag + (long)(rowA0 + r) * K + k0 + kc * 8);
    }
    for (int c = tid; c < BN * 4; c += 256) {
      int r = c >> 2, kc = c & 3;
      *reinterpret_cast<bf16x8*>(&Bs[r * LDT + kc * 8]) =
          *reinterpret_cast<const bf16x8*>(&Bg[(long)(rowB0 + r) * K + k0 + kc * 8]);
    }
    __syncthreads();
    bf16x8 af[2], bfv[2];
#pragma unroll
    for (int i = 0; i < 2; i++)
      af[i] = *reinterpret_cast<bf16x8*>(&As[(wr * 32 + i * 16 + l16) * LDT + quad * 8]);
#pragma unroll
    for (int j = 0; j < 2; j++)
      bfv[j] = *reinterpret_cast<bf16x8*>(&Bs[(wc * 32 + j * 16 + l16) * LDT + quad * 8]);
#pragma unroll
    for (int i = 0; i < 2; i++)
#pragma unroll
      for (int j = 0; j < 2; j++)
        acc[i][j] = __builtin_amdgcn_mfma_f32_16x16x32_bf16(af[i], bfv[j], acc[i][j], 0, 0, 0);
    __syncthreads();
  }
#pragma unroll
  for (int i = 0; i < 2; i++)
#pragma unroll
    for (int j = 0; j < 2; j++)
#pragma unroll
      for (int r = 0; r < 4; r++) {
        int row = rowA0 + wr * 32 + i * 16 + quad * 4 + r;
        int col = rowB0 + wc * 32 + j * 16 + l16;
        Mp[(long)kz * M * Nn + (long)row * Nn + col] = acc[i][j][r];
      }
}

__global__ __launch_bounds__(256) void mb_combine(
    const float* __restrict__ Mp, bf16_t* __restrict__ Mb, int total) {
  int i = blockIdx.x * 256 + threadIdx.x;
  if (i >= total) return;
  float s = 0.f;
#pragma unroll
  for (int z = 0; z < 8; z++) s += Mp[(long)z * total + i];
  Mb[i] = f2b(s);
}

// ---------------------------------------------------------------------------
// Split-precision (hi/lo) down-proj GEMM, f32 input (fallback path).
// ---------------------------------------------------------------------------
__global__ __launch_bounds__(256) void gemm_dn_hl(
    const float* __restrict__ Ag, const float* __restrict__ Bg,
    float* __restrict__ Cg, int M, int Nn, int K) {
  constexpr int BM = 128, BN = 128, LDT = 40;
  __shared__ alignas(16) bf16_t Ah[BM * LDT];
  __shared__ alignas(16) bf16_t Al[BM * LDT];
  __shared__ alignas(16) bf16_t Bh[BN * LDT];
  __shared__ alignas(16) bf16_t Bl[BN * LDT];

  const int tid = threadIdx.x;
  const int wave = tid >> 6, lane = tid & 63;
  const int wr = wave >> 1, wc = wave & 1;
  const int quad = lane >> 4, l16 = lane & 15;
  const int rowA0 = blockIdx.y * BM, rowB0 = blockIdx.x * BN;

  f32x4 acc[4][4] = {};

  for (int k0 = 0; k0 < K; k0 += 32) {
    for (int c = tid; c < BM * 4; c += 256) {
      int r = c >> 2, kc = c & 3;
      bf16x8 h, l;
      split8(&Ag[(long)(rowA0 + r) * K + k0 + kc * 8], h, l);
      *reinterpret_cast<bf16x8*>(&Ah[r * LDT + kc * 8]) = h;
      *reinterpret_cast<bf16x8*>(&Al[r * LDT + kc * 8]) = l;
    }
    for (int c = tid; c < BN * 4; c += 256) {
      int r = c >> 2, kc = c & 3;
      bf16x8 h, l;
      split8(&Bg[(long)(rowB0 + r) * K + k0 + kc * 8], h, l);
      *reinterpret_cast<bf16x8*>(&Bh[r * LDT + kc * 8]) = h;
      *reinterpret_cast<bf16x8*>(&Bl[r * LDT + kc * 8]) = l;
    }
    __syncthreads();
    bf16x8 afh[4], afl[4], bfh[4], bfl[4];
#pragma unroll
    for (int i = 0; i < 4; i++) {
      int ro = (wr * 64 + i * 16 + l16) * LDT + quad * 8;
      afh[i] = *reinterpret_cast<bf16x8*>(&Ah[ro]);
      afl[i] = *reinterpret_cast<bf16x8*>(&Al[ro]);
    }
#pragma unroll
    for (int j = 0; j < 4; j++) {
      int ro = (wc * 64 + j * 16 + l16) * LDT + quad * 8;
      bfh[j] = *reinterpret_cast<bf16x8*>(&Bh[ro]);
      bfl[j] = *reinterpret_cast<bf16x8*>(&Bl[ro]);
    }
#pragma unroll
    for (int i = 0; i < 4; i++)
#pragma unroll
      for (int j = 0; j < 4; j++) {
        acc[i][j] = __builtin_amdgcn_mfma_f32_16x16x32_bf16(afh[i], bfh[j], acc[i][j], 0, 0, 0);
        acc[i][j] = __builtin_amdgcn_mfma_f32_16x16x32_bf16(afh[i], bfl[j], acc[i][j], 0, 0, 0);
        acc[i][j] = __builtin_amdgcn_mfma_f32_16x16x32_bf16(afl[i], bfh[j], acc[i][j], 0, 0, 0);
      }
    __syncthreads();
  }

#pragma unroll
  for (int i = 0; i < 4; i++)
#pragma unroll
    for (int j = 0; j < 4; j++)
#pragma unroll
      for (int r = 0; r < 4; r++) {
        int row = rowA0 + wr * 64 + i * 16 + quad * 4 + r;
        int col = rowB0 + wc * 64 + j * 16 + l16;
        Cg[(long)row * Nn + col] = acc[i][j][r];
      }
}

// ---------------------------------------------------------------------------
// Down-proj GEMM from PRE-SPLIT hi/lo bf16 inputs (big-ws path).
// ---------------------------------------------------------------------------
__global__ __launch_bounds__(256) void gemm_dn_b(
    const bf16_t* __restrict__ Ahg, const bf16_t* __restrict__ Alg,
    const bf16_t* __restrict__ Bhg, const bf16_t* __restrict__ Blg,
    float* __restrict__ Cg, int M, int Nn, int K) {
  constexpr int BM = 128, BN = 128, LDT = 40;
  __shared__ alignas(16) bf16_t Ah[BM * LDT];
  __shared__ alignas(16) bf16_t Al[BM * LDT];
  __shared__ alignas(16) bf16_t Bh[BN * LDT];
  __shared__ alignas(16) bf16_t Bl[BN * LDT];

  const int tid = threadIdx.x;
  const int wave = tid >> 6, lane = tid & 63;
  const int wr = wave >> 1, wc = wave & 1;
  const int quad = lane >> 4, l16 = lane & 15;
  const int rowA0 = blockIdx.y * BM, rowB0 = blockIdx.x * BN;

  f32x4 acc[4][4] = {};

  for (int k0 = 0; k0 < K; k0 += 32) {
    for (int c = tid; c < BM * 4; c += 256) {
      int r = c >> 2, kc = c & 3;
      long idx = (long)(rowA0 + r) * K + k0 + kc * 8;
      int lo = r * LDT + kc * 8;
      *reinterpret_cast<bf16x8*>(&Ah[lo]) = *reinterpret_cast<const bf16x8*>(&Ahg[idx]);
      *reinterpret_cast<bf16x8*>(&Al[lo]) = *reinterpret_cast<const bf16x8*>(&Alg[idx]);
    }
    for (int c = tid; c < BN * 4; c += 256) {
      int r = c >> 2, kc = c & 3;
      long idx = (long)(rowB0 + r) * K + k0 + kc * 8;
      int lo = r * LDT + kc * 8;
      *reinterpret_cast<bf16x8*>(&Bh[lo]) = *reinterpret_cast<const bf16x8*>(&Bhg[idx]);
      *reinterpret_cast<bf16x8*>(&Bl[lo]) = *reinterpret_cast<const bf16x8*>(&Blg[idx]);
    }
    __syncthreads();
    bf16x8 afh[4], afl[4], bfh[4], bfl[4];
#pragma unroll
    for (int i = 0; i < 4; i++) {
      int ro = (wr * 64 + i * 16 + l16) * LDT + quad * 8;
      afh[i] = *reinterpret_cast<bf16x8*>(&Ah[ro]);
      afl[i] = *reinterpret_cast<bf16x8*>(&Al[ro]);
    }
#pragma unroll
    for (int j = 0; j < 4; j++) {
      int ro = (wc * 64 + j * 16 + l16) * LDT + quad * 8;
      bfh[j] = *reinterpret_cast<bf16x8*>(&Bh[ro]);
      bfl[j] = *reinterpret_cast<bf16x8*>(&Bl[ro]);
    }
#pragma unroll
    for (int i = 0; i < 4; i++)
#pragma unroll
      for (int j = 0; j < 4; j++) {
        acc[i][j] = __builtin_amdgcn_mfma_f32_16x16x32_bf16(afh[i], bfh[j], acc[i][j], 0, 0, 0);
        acc[i][j] = __builtin_amdgcn_mfma_f32_16x16x32_bf16(afh[i], bfl[j], acc[i][j], 0, 0, 0);
        acc[i][j] = __builtin_amdgcn_mfma_f32_16x16x32_bf16(afl[i], bfh[j], acc[i][j], 0, 0, 0);
      }
    __syncthreads();
  }

#pragma unroll
  for (int i = 0; i < 4; i++)
#pragma unroll
    for (int j = 0; j < 4; j++)
#pragma unroll
      for (int r = 0; r < 4; r++) {
        int row = rowA0 + wr * 64 + i * 16 + quad * 4 + r;
        int col = rowB0 + wc * 64 + j * 16 + l16;
        Cg[(long)row * Nn + col] = acc[i][j][r];
      }
}

// ---------------------------------------------------------------------------
// Split-precision fused gate/up, f32 input (fallback path): writes f32.
// ---------------------------------------------------------------------------
__global__ __launch_bounds__(256) void gemm_gu_hl(
    const float* __restrict__ x, const float* __restrict__ Wg,
    const float* __restrict__ Wu, float* __restrict__ Cg, int M, int Nn, int K) {
  constexpr int BM = 128, BN = 64, LDT = 40;
  __shared__ alignas(16) bf16_t Ah[BM * LDT];
  __shared__ alignas(16) bf16_t Al[BM * LDT];
  __shared__ alignas(16) bf16_t B1h[BN * LDT];
  __shared__ alignas(16) bf16_t B1l[BN * LDT];
  __shared__ alignas(16) bf16_t B2h[BN * LDT];
  __shared__ alignas(16) bf16_t B2l[BN * LDT];

  const int tid = threadIdx.x;
  const int wave = tid >> 6, lane = tid & 63;
  const int wr = wave >> 1, wc = wave & 1;
  const int quad = lane >> 4, l16 = lane & 15;
  const int rowA0 = blockIdx.y * BM, rowB0 = blockIdx.x * BN;

  f32x4 ag[4][2] = {}, au[4][2] = {};

  for (int k0 = 0; k0 < K; k0 += 32) {
    for (int c = tid; c < BM * 4; c += 256) {
      int r = c >> 2, kc = c & 3;
      bf16x8 h, l;
      split8(&x[(long)(rowA0 + r) * K + k0 + kc * 8], h, l);
      *reinterpret_cast<bf16x8*>(&Ah[r * LDT + kc * 8]) = h;
      *reinterpret_cast<bf16x8*>(&Al[r * LDT + kc * 8]) = l;
    }
    for (int c = tid; c < BN * 4; c += 256) {
      int r = c >> 2, kc = c & 3;
      long idx = (long)(rowB0 + r) * K + k0 + kc * 8;
      bf16x8 h, l;
      split8(&Wg[idx], h, l);
      *reinterpret_cast<bf16x8*>(&B1h[r * LDT + kc * 8]) = h;
      *reinterpret_cast<bf16x8*>(&B1l[r * LDT + kc * 8]) = l;
      split8(&Wu[idx], h, l);
      *reinterpret_cast<bf16x8*>(&B2h[r * LDT + kc * 8]) = h;
      *reinterpret_cast<bf16x8*>(&B2l[r * LDT + kc * 8]) = l;
    }
    __syncthreads();
    bf16x8 afh[4], afl[4], b1h[2], b1l[2], b2h[2], b2l[2];
#pragma unroll
    for (int i = 0; i < 4; i++) {
      int ro = (wr * 64 + i * 16 + l16) * LDT + quad * 8;
      afh[i] = *reinterpret_cast<bf16x8*>(&Ah[ro]);
      afl[i] = *reinterpret_cast<bf16x8*>(&Al[ro]);
    }
#pragma unroll
    for (int j = 0; j < 2; j++) {
      int ro = (wc * 32 + j * 16 + l16) * LDT + quad * 8;
      b1h[j] = *reinterpret_cast<bf16x8*>(&B1h[ro]);
      b1l[j] = *reinterpret_cast<bf16x8*>(&B1l[ro]);
      b2h[j] = *reinterpret_cast<bf16x8*>(&B2h[ro]);
      b2l[j] = *reinterpret_cast<bf16x8*>(&B2l[ro]);
    }
#pragma unroll
    for (int i = 0; i < 4; i++)
#pragma unroll
      for (int j = 0; j < 2; j++) {
        ag[i][j] = __builtin_amdgcn_mfma_f32_16x16x32_bf16(afh[i], b1h[j], ag[i][j], 0, 0, 0);
        ag[i][j] = __builtin_amdgcn_mfma_f32_16x16x32_bf16(afh[i], b1l[j], ag[i][j], 0, 0, 0);
        ag[i][j] = __builtin_amdgcn_mfma_f32_16x16x32_bf16(afl[i], b1h[j], ag[i][j], 0, 0, 0);
        au[i][j] = __builtin_amdgcn_mfma_f32_16x16x32_bf16(afh[i], b2h[j], au[i][j], 0, 0, 0);
        au[i][j] = __builtin_amdgcn_mfma_f32_16x16x32_bf16(afh[i], b2l[j], au[i][j], 0, 0, 0);
        au[i][j] = __builtin_amdgcn_mfma_f32_16x16x32_bf16(afl[i], b2h[j], au[i][j], 0, 0, 0);
      }
    __syncthreads();
  }

#pragma unroll
  for (int i = 0; i < 4; i++)
#pragma unroll
    for (int j = 0; j < 2; j++)
#pragma unroll
      for (int r = 0; r < 4; r++) {
        int row = rowA0 + wr * 64 + i * 16 + quad * 4 + r;
        int col = rowB0 + wc * 32 + j * 16 + l16;
        Cg[(long)row * Nn + col] = siluf(ag[i][j][r]) * au[i][j][r];
      }
}

// ---------------------------------------------------------------------------
// Fused gate/up from PRE-SPLIT hi/lo bf16 inputs (big-ws path).
// ---------------------------------------------------------------------------
__global__ __launch_bounds__(256) void gemm_gu_b(
    const bf16_t* __restrict__ Ahg, const bf16_t* __restrict__ Alg,
    const bf16_t* __restrict__ B1hg, const bf16_t* __restrict__ B1lg,
    const bf16_t* __restrict__ B2hg, const bf16_t* __restrict__ B2lg,
    bf16_t* __restrict__ Hh, bf16_t* __restrict__ Hl, int M, int Nn, int K) {
  constexpr int BM = 128, BN = 64, LDT = 40;
  __shared__ alignas(16) bf16_t Ah[BM * LDT];
  __shared__ alignas(16) bf16_t Al[BM * LDT];
  __shared__ alignas(16) bf16_t B1h[BN * LDT];
  __shared__ alignas(16) bf16_t B1l[BN * LDT];
  __shared__ alignas(16) bf16_t B2h[BN * LDT];
  __shared__ alignas(16) bf16_t B2l[BN * LDT];

  const int tid = threadIdx.x;
  const int wave = tid >> 6, lane = tid & 63;
  const int wr = wave >> 1, wc = wave & 1;
  const int quad = lane >> 4, l16 = lane & 15;
  const int rowA0 = blockIdx.y * BM, rowB0 = blockIdx.x * BN;

  f32x4 ag[4][2] = {}, au[4][2] = {};

  for (int k0 = 0; k0 < K; k0 += 32) {
    for (int c = tid; c < BM * 4; c += 256) {
      int r = c >> 2, kc = c & 3;
      long idx = (long)(rowA0 + r) * K + k0 + kc * 8;
      int lo = r * LDT + kc * 8;
      *reinterpret_cast<bf16x8*>(&Ah[lo]) = *reinterpret_cast<const bf16x8*>(&Ahg[idx]);
      *reinterpret_cast<bf16x8*>(&Al[lo]) = *reinterpret_cast<const bf16x8*>(&Alg[idx]);
    }
    for (int c = tid; c < BN * 4; c += 256) {
      int r = c >> 2, kc = c & 3;
      long idx = (long)(rowB0 + r) * K + k0 + kc * 8;
      int lo = r * LDT + kc * 8;
      *reinterpret_cast<bf16x8*>(&B1h[lo]) = *reinterpret_cast<const bf16x8*>(&B1hg[idx]);
      *reinterpret_cast<bf16x8*>(&B1l[lo]) = *reinterpret_cast<const bf16x8*>(&B1lg[idx]);
      *reinterpret_cast<bf16x8*>(&B2h[lo]) = *reinterpret_cast<const bf16x8*>(&B2hg[idx]);
      *reinterpret_cast<bf16x8*>(&B2l[lo]) = *reinterpret_cast<const bf16x8*>(&B2lg[idx]);
    }
    __syncthreads();
    bf16x8 afh[4], afl[4], b1h[2], b1l[2], b2h[2], b2l[2];
#pragma unroll
    for (int i = 0; i < 4; i++) {
      int ro = (wr * 64 + i * 16 + l16) * LDT + quad * 8;
      afh[i] = *reinterpret_cast<bf16x8*>(&Ah[ro]);
      afl[i] = *reinterpret_cast<bf16x8*>(&Al[ro]);
    }
#pragma unroll
    for (int j = 0; j < 2; j++) {
      int ro = (wc * 32 + j * 16 + l16) * LDT + quad * 8;
      b1h[j] = *reinterpret_cast<bf16x8*>(&B1h[ro]);
      b1l[j] = *reinterpret_cast<bf16x8*>(&B1l[ro]);
      b2h[j] = *reinterpret_cast<bf16x8*>(&B2h[ro]);
      b2l[j] = *reinterpret_cast<bf16x8*>(&B2l[ro]);
    }
#pragma unroll
    for (int i = 0; i < 4; i++)
#pragma unroll
      for (int j = 0; j < 2; j++) {
        ag[i][j] = __builtin_amdgcn_mfma_f32_16x16x32_bf16(afh[i], b1h[j], ag[i][j], 0, 0, 0);
        ag[i][j] = __builtin_amdgcn_mfma_f32_16x16x32_bf16(afh[i], b1l[j], ag[i][j], 0, 0, 0);
        ag[i][j] = __builtin_amdgcn_mfma_f32_16x16x32_bf16(afl[i], b1h[j], ag[i][j], 0, 0, 0);
        au[i][j] = __builtin_amdgcn_mfma_f32_16x16x32_bf16(afh[i], b2h[j], au[i][j], 0, 0, 0);
        au[i][j] = __builtin_amdgcn_mfma_f32_16x16x32_bf16(afh[i], b2l[j], au[i][j], 0, 0, 0);
        au[i][j] = __builtin_amdgcn_mfma_f32_16x16x32_bf16(afl[i], b2h[j], au[i][j], 0, 0, 0);
      }
    __syncthreads();
  }

#pragma unroll
  for (int i = 0; i < 4; i++)
#pragma unroll
    for (int j = 0; j < 2; j++)
#pragma unroll
      for (int r = 0; r < 4; r++) {
        int row = rowA0 + wr * 64 + i * 16 + quad * 4 + r;
        int col = rowB0 + wc * 32 + j * 16 + l16;
        long o = (long)row * Nn + col;
        float v = siluf(ag[i][j][r]) * au[i][j][r];
        bf16_t hh = f2b(v);
        Hh[o] = hh;
        Hl[o] = f2b(v - b2f(hh));
      }
}

// ---------------------------------------------------------------------------
// Router (no global atomics, per-block partials).
// ---------------------------------------------------------------------------
__global__ __launch_bounds__(256) void router_kernel(
    const float* __restrict__ x, const float* __restrict__ Wgr,
    const float* __restrict__ Wer, int* __restrict__ eidx,
    float* __restrict__ fw, float* __restrict__ wsum,
    float* __restrict__ lpart) {
  __shared__ float part[4][12];
  const int wv = threadIdx.x >> 6;
  const int lane = threadIdx.x & 63;
  const int token = blockIdx.x * 4 + wv;
  if (lane < 12) part[wv][lane] = 0.f;
  const float* xp = x + (long)token * D;
  float xr[16];
#pragma unroll
  for (int i = 0; i < 16; i++) xr[i] = xp[lane + i * 64];
  float dots[6];
#pragma unroll
  for (int w = 0; w < 6; w++) {
    const float* wp = (w < 2) ? (Wgr + (long)w * D) : (Wer + (long)(w - 2) * D);
    float s = 0.f;
#pragma unroll
    for (int i = 0; i < 16; i++) s += xr[i] * wp[lane + i * 64];
#pragma unroll
    for (int off = 32; off; off >>= 1) s += __shfl_xor(s, off);
    dots[w] = s;
  }
  if (lane == 0) {
    float gl0 = dots[0], gl1 = dots[1];
    float mg = fmaxf(gl0, gl1);
    float e0 = expf(gl0 - mg), e1 = expf(gl1 - mg);
    float inv = 1.f / (e0 + e1);
    float gp0 = e0 * inv, gp1 = e1 * inv;
    int gi = (gp1 > gp0) ? 1 : 0;
    float gw = gi ? gp1 : gp0;
    float el[4] = {dots[2], dots[3], dots[4], dots[5]};
    float me = fmaxf(fmaxf(el[0], el[1]), fmaxf(el[2], el[3]));
    float ep[4], es = 0.f;
#pragma unroll
    for (int j = 0; j < 4; j++) { ep[j] = expf(el[j] - me); es += ep[j]; }
    float inve = 1.f / es;
#pragma unroll
    for (int j = 0; j < 4; j++) ep[j] *= inve;
    int i1 = 0;
    for (int j = 1; j < 4; j++) if (ep[j] > ep[i1]) i1 = j;
    int i2 = (i1 == 0) ? 1 : 0;
    for (int j = 0; j < 4; j++) if (j != i1 && j != i2 && ep[j] > ep[i2]) i2 = j;
    float l1 = ep[i1], l2 = ep[i2];
    float ils = 1.f / (l1 + l2 + 1e-7f);
    float f1 = gw * l1 * ils, f2 = gw * l2 * ils;
    eidx[token * 2] = gi * 4 + i1;
    eidx[token * 2 + 1] = gi * 4 + i2;
    fw[token * 2] = f1;
    fw[token * 2 + 1] = f2;
    wsum[token] = f1 + f2;
    part[wv][gi * 4 + i1] = f1;
    part[wv][gi * 4 + i2] = f2;
    part[wv][8] = gl0 * gl0 + gl1 * gl1;
    part[wv][9] = el[0] * el[0] + el[1] * el[1] + el[2] * el[2] + el[3] * el[3];
  }
  __syncthreads();
  if (threadIdx.x < 12) {
    lpart[(long)blockIdx.x * 12 + threadIdx.x] =
        part[0][threadIdx.x] + part[1][threadIdx.x] +
        part[2][threadIdx.x] + part[3][threadIdx.x];
  }
}

// ---------------------------------------------------------------------------
// Row LayerNorm over A=128 (bf16 in ws, f32 g/b, bf16 out).
// ---------------------------------------------------------------------------
__global__ __launch_bounds__(256) void ln_rows(
    const bf16_t* __restrict__ in, const float* __restrict__ g,
    const float* __restrict__ b, bf16_t* __restrict__ out) {
  const int row = blockIdx.x * 4 + (threadIdx.x >> 6);
  const int lane = threadIdx.x & 63;
  const bf16_t* p = in + (long)row * A;
  float x0 = b2f(p[lane]), x1 = b2f(p[lane + 64]);
  float s = x0 + x1;
#pragma unroll
  for (int off = 32; off; off >>= 1) s += __shfl_xor(s, off);
  float mean = s * (1.f / 128.f);
  float d0 = x0 - mean, d1 = x1 - mean;
  float q = d0 * d0 + d1 * d1;
#pragma unroll
  for (int off = 32; off; off >>= 1) q += __shfl_xor(q, off);
  float r = rsqrtf(q * (1.f / 128.f) + 1e-5f);
  bf16_t* po = out + (long)row * A;
  po[lane] = f2b(d0 * r * g[lane] + b[lane]);
  po[lane + 64] = f2b(d1 * r * g[lane + 64] + b[lane + 64]);
}

// ---------------------------------------------------------------------------
// Transpose [z,R,C] -> [z,C,R], bf16 out; input f32 (isf=1) or bf16.
// ---------------------------------------------------------------------------
__global__ __launch_bounds__(256) void transpose2d(
    const void* __restrict__ in, bf16_t* __restrict__ out, int R, int C, int isf) {
  __shared__ bf16_t t[32][33];
  const long zb = blockIdx.z;
  const long ib = zb * (long)R * C;
  bf16_t* op = out + zb * (long)R * C;
  const int r0 = blockIdx.y * 32, c0 = blockIdx.x * 32;
  const int tx = threadIdx.x & 31, ty = threadIdx.x >> 5;
#pragma unroll
  for (int i = 0; i < 4; i++) {
    long idx = ib + (long)(r0 + ty + i * 8) * C + c0 + tx;
    t[ty + i * 8][tx] = isf ? f2b(reinterpret_cast<const float*>(in)[idx])
                            : reinterpret_cast<const bf16_t*>(in)[idx];
  }
  __syncthreads();
#pragma unroll
  for (int i = 0; i < 4; i++) op[(long)(c0 + ty + i * 8) * R + r0 + tx] = t[tx][ty + i * 8];
}

// ---------------------------------------------------------------------------
// Expert branch: coalesced via pre-transposed WeaT[e][a][c] (bf16).
// ---------------------------------------------------------------------------
__global__ __launch_bounds__(128) void expert_adapt(
    const bf16_t* __restrict__ h0, const bf16_t* __restrict__ WeaT,
    const float* __restrict__ ln_eg, const float* __restrict__ ln_eb,
    const int* __restrict__ eidx, const float* __restrict__ fw,
    bf16_t* __restrict__ hw) {
  const int n = blockIdx.x;
  const int c = threadIdx.x;
  __shared__ float h0s[128];
  __shared__ float red[4];
  h0s[c] = b2f(h0[(long)n * A + c]);
  __syncthreads();
  float out = 0.f;
  for (int k = 0; k < 2; k++) {
    int e = eidx[n * 2 + k];
    e = min(max(e, 0), E - 1);
    float w = fw[n * 2 + k];
    const bf16_t* Wc = WeaT + (long)e * A * A + c;
    float t = 0.f;
#pragma unroll 8
    for (int a = 0; a < 128; a++) t += b2f(Wc[(long)a * A]) * h0s[a];
    float s = t, q = t * t;
#pragma unroll
    for (int off = 32; off; off >>= 1) { s += __shfl_xor(s, off); q += __shfl_xor(q, off); }
    if ((c & 63) == 0) { red[(c >> 6) * 2] = s; red[(c >> 6) * 2 + 1] = q; }
    __syncthreads();
    float Sx = red[0] + red[2], Qx = red[1] + red[3];
    float mean = Sx * (1.f / 128.f);
    float var = Qx * (1.f / 128.f) - mean * mean;
    float r = rsqrtf(var + 1e-5f);
    out += w * ((t - mean) * r * ln_eg[e * A + c] + ln_eb[e * A + c]);
    __syncthreads();
  }
  hw[(long)n * A + c] = f2b(out);
}

// ---------------------------------------------------------------------------
// Loss finalize: reduce 2048 per-block 12-float partials, then scalar.
// ---------------------------------------------------------------------------
__global__ __launch_bounds__(256) void finalize_loss(
    const float* __restrict__ lpart, int nblk, float* __restrict__ outv) {
  float acc[10] = {};
  for (int b = threadIdx.x; b < nblk; b += 256) {
    const float* p = lpart + (long)b * 12;
#pragma unroll
    for (int c = 0; c < 10; c++) acc[c] += p[c];
  }
  __shared__ float red[10][4];
  const int lane = threadIdx.x & 63, wv = threadIdx.x >> 6;
#pragma unroll
  for (int c = 0; c < 10; c++) {
    float s = acc[c];
#pragma unroll
    for (int off = 32; off; off >>= 1) s += __shfl_xor(s, off);
    if (lane == 0) red[c][wv] = s;
  }
  __syncthreads();
  if (threadIdx.x == 0) {
    float loss[10];
#pragma unroll
    for (int c = 0; c < 10; c++)
      loss[c] = red[c][0] + red[c][1] + red[c][2] + red[c][3];
    float tl = 0.f;
    for (int e = 0; e < 8; e++) tl += loss[e];
    float target = tl / 8.f;
    float mse = 0.f;
    for (int e = 0; e < 8; e++) { float d = loss[e] - target; mse += d * d; }
    mse *= (1.f / 8.f);
    outv[0] = 0.001f * (mse + loss[8] / (float)(N * 2) + loss[9] / (float)(N * 4));
  }
}

// ---------------------------------------------------------------------------
extern "C" void kernel_launch(void* const* d_in, const int* in_sizes, int n_in,
                              void* d_out, int out_size, void* d_ws, size_t ws_size,
                              hipStream_t stream) {
  const float* x = (const float*)d_in[0];
  const float* Wu = (const float*)d_in[1];
  const float* Wg = (const float*)d_in[2];
  const float* Wd = (const float*)d_in[3];
  const float* Wpre = (const float*)d_in[4];
  const float* Wpost = (const float*)d_in[5];
  const float* ln_g = (const float*)d_in[6];
  const float* ln_b = (const float*)d_in[7];
  const float* Wap = (const float*)d_in[8];
  const float* Wea = (const float*)d_in[9];
  const float* ln_eg = (const float*)d_in[10];
  const float* ln_eb = (const float*)d_in[11];
  const float* Wep = (const float*)d_in[12];
  const float* Wop = (const float*)d_in[13];
  const float* Wgr = (const float*)d_in[14];
  const float* Wer = (const float*)d_in[15];
  float* out = (float*)d_out;

  char* ws = (char*)d_ws;
  size_t off = 0;
  auto alloc = [&](size_t bytes) { char* p = ws + off; off += (bytes + 255) & ~size_t(255); return p; };
  // Common allocations (~18.5 MB)
  float* lpart = (float*)alloc((size_t)(N / 4) * 12 * 4);
  float* wsum = (float*)alloc((size_t)N * 4);
  float* fwb = (float*)alloc((size_t)N * 2 * 4);
  int* eidx = (int*)alloc((size_t)N * 2 * 4);
  bf16_t* Mb = (bf16_t*)alloc((size_t)D * A * 2);
  float* Mp = (float*)alloc((size_t)8 * D * A * 4);     // 4 MB split-K partials
  bf16_t* WepT = (bf16_t*)alloc((size_t)H * A * 2);
  bf16_t* hwb = (bf16_t*)alloc((size_t)N * A * 2);
  bf16_t* h0b = (bf16_t*)alloc((size_t)N * A * 2);
  bf16_t* aib = (bf16_t*)alloc((size_t)N * A * 2);
  bf16_t* scrA = (bf16_t*)alloc((size_t)N * A * 2);     // aopre -> aiT
  bf16_t* aob = (bf16_t*)alloc((size_t)N * A * 2);
  bf16_t* adpreb = (bf16_t*)alloc((size_t)N * A * 2);   // own buffer (fused kernel
                                                        // reads aob concurrently)
  bf16_t* WeaT = (bf16_t*)alloc((size_t)E * A * A * 2);
  bf16_t* aopre = scrA;
  bf16_t* aiT = scrA;

  // Big path: pre-split hi/lo buffers (+120 MB).
  const bool big = ws_size >= ((size_t)140 << 20);
  float* hiddenF = nullptr;
  bf16_t *xh = nullptr, *xl = nullptr;
  bf16_t *Wgh = nullptr, *Wgl = nullptr, *Wuh = nullptr, *Wul = nullptr;
  bf16_t *Wdh = nullptr, *Wdl = nullptr, *Hh = nullptr, *Hl = nullptr;
  if (big) {
    xh = (bf16_t*)alloc((size_t)N * D * 2);
    xl = (bf16_t*)alloc((size_t)N * D * 2);
    Wgh = (bf16_t*)alloc((size_t)H * D * 2);
    Wgl = (bf16_t*)alloc((size_t)H * D * 2);
    Wuh = (bf16_t*)alloc((size_t)H * D * 2);
    Wul = (bf16_t*)alloc((size_t)H * D * 2);
    Wdh = (bf16_t*)alloc((size_t)D * H * 2);
    Wdl = (bf16_t*)alloc((size_t)D * H * 2);
    Hh = (bf16_t*)alloc((size_t)N * H * 2);
    Hl = (bf16_t*)alloc((size_t)N * H * 2);
  } else {
    hiddenF = (float*)alloc((size_t)N * H * 4);
  }
  (void)ws_size; (void)in_sizes; (void)n_in; (void)out_size;

  const dim3 blk(256);

  router_kernel<<<dim3(N / 4), blk, 0, stream>>>(x, Wgr, Wer, eidx, fwb, wsum, lpart);
  transpose2d<<<dim3(A / 32, A / 32, E), blk, 0, stream>>>(Wea, WeaT, A, A, 1);

  if (big) {
    split_pass<<<dim3(2048), blk, 0, stream>>>(x, xh, xl, (long)N * D / 8);
    split3_pass<<<dim3(1024), blk, 0, stream>>>(
        Wg, Wgh, Wgl, Wu, Wuh, Wul, Wd, Wdh, Wdl, (long)H * D / 8);
    gemm_gu_b<<<dim3(H / 64, N / 128), blk, 0, stream>>>(
        xh, xl, Wgh, Wgl, Wuh, Wul, Hh, Hl, N, H, D);
    // h0 = x@Wpre^T  [N,A] K=D   (WM=16: 512 blocks for TLP)
    gemm_nt_b<16, 32, 0><<<dim3(A / 64, N / 32), blk, 0, stream>>>(
        xh, Wpre, h0b, nullptr, N, A, D, nullptr, 0, 1);
    ln_rows<<<dim3(N / 4), blk, 0, stream>>>(h0b, ln_g, ln_b, aib);
    // ao_pre = hidden@Wpost^T  [N,A] K=H
    gemm_nt_b<16, 32, 0><<<dim3(A / 64, N / 32), blk, 0, stream>>>(
        Hh, Wpost, aopre, nullptr, N, A, H, nullptr, 0, 1);
    ln_rows<<<dim3(N / 4), blk, 0, stream>>>(aopre, ln_g, ln_b, aob);
    transpose2d<<<dim3(A / 32, S / 32, Bb), blk, 0, stream>>>(aib, aiT, S, A, 0);
    // adpre = silu(clip(ai@ao^T)) @ ai  (fused flash-style, all batches)
    fused_adapt<<<dim3(S / 64, Bb), blk, 0, stream>>>(aib, aob, aiT, adpreb);
    // hidden += 0.1 * adpre@Wap^T  (hi/lo RMW)
    gemm_nt_b<64, 64, 4><<<dim3(H / 128, N / 128), blk, 0, stream>>>(
        adpreb, Wap, Hh, Hl, N, H, A, nullptr, 0, 1);
    gemm_dn_b<<<dim3(D / 128, N / 128), blk, 0, stream>>>(
        Hh, Hl, Wdh, Wdl, out, N, D, H);
  } else {
    gemm_gu_hl<<<dim3(H / 64, N / 128), blk, 0, stream>>>(x, Wg, Wu, hiddenF, N, H, D);
    gemm_nt_b<16, 32, 0><<<dim3(A / 64, N / 32), blk, 0, stream>>>(
        x, Wpre, h0b, nullptr, N, A, D, nullptr, 1, 1);
    ln_rows<<<dim3(N / 4), blk, 0, stream>>>(h0b, ln_g, ln_b, aib);
    gemm_nt_b<16, 32, 0><<<dim3(A / 64, N / 32), blk, 0, stream>>>(
        hiddenF, Wpost, aopre, nullptr, N, A, H, nullptr, 1, 1);
    ln_rows<<<dim3(N / 4), blk, 0, stream>>>(aopre, ln_g, ln_b, aob);
    transpose2d<<<dim3(A / 32, S / 32, Bb), blk, 0, stream>>>(aib, aiT, S, A, 0);
    fused_adapt<<<dim3(S / 64, Bb), blk, 0, stream>>>(aib, aob, aiT, adpreb);
    gemm_nt_b<64, 64, 2><<<dim3(H / 128, N / 128), blk, 0, stream>>>(
        adpreb, Wap, hiddenF, nullptr, N, H, A, nullptr, 0, 1);
    gemm_dn_hl<<<dim3(D / 128, N / 128), blk, 0, stream>>>(hiddenF, Wd, out, N, D, H);
  }

  // Common tail
  transpose2d<<<dim3(A / 32, H / 32, 1), blk, 0, stream>>>(Wep, WepT, H, A, 1);
  // M = Wop@Wep  [D,A] K=H  split-K x8 -> f32 partials -> bf16
  gemm_mb_splitk<<<dim3(A / 64, D / 64, 8), blk, 0, stream>>>(
      Wop, WepT, Mp, D, A, H);
  mb_combine<<<dim3((D * A + 255) / 256), blk, 0, stream>>>(Mp, Mb, D * A);
  expert_adapt<<<dim3(N), dim3(128), 0, stream>>>(h0b, WeaT, ln_eg, ln_eb, eidx, fwb, hwb);
  gemm_nt_b<64, 64, 3><<<dim3(D / 128, N / 128), blk, 0, stream>>>(
      hwb, Mb, out, nullptr, N, D, A, wsum, 0, 0);
  finalize_loss<<<dim3(1), blk, 0, stream>>>(lpart, N / 4, out + (size_t)N * D);
}

// Round 5
// 790.018 us; speedup vs baseline: 1.9219x; 1.0903x over previous
//
#include <hip/hip_runtime.h>
#include <math.h>

// ---------------------------------------------------------------------------
// MoE layer, round 12: global_load_lds staging for gu/dn (Common-mistake #1).
// R11 profile: gemm_gu_b 233us pinned at the 2-barrier ceiling, VALUBusy 27%
// from register-roundtrip staging, 3.35e7 LDS bank-conflict cycles.
// Fix: pre-split passes now emit TILED chunk-swizzled layouts ([R/TR][K/32]
// [TR][4x16B], chunk p holds source chunk p^(r&3)); gu stages all 6 streams
// and dn all 4 streams via global_load_lds width=16 (linear dest + pre-
// swizzled source + swizzled ds_read, rule #21). gu epilogue writes Hh/Hl
// tiled; aopre/h0/MODE4 read tiled via shared tidx(). Bit-exact vs R11.
// B=4, S=2048, D=1024, H=2048, A=128, E=8, N=8192.
// ---------------------------------------------------------------------------

typedef __bf16 bf16_t;
typedef __attribute__((ext_vector_type(8))) __bf16 bf16x8;
typedef __attribute__((ext_vector_type(4))) float f32x4;

__device__ __forceinline__ float b2f(bf16_t v) { return (float)v; }
__device__ __forceinline__ bf16_t f2b(float v) { return (bf16_t)v; }
__device__ __forceinline__ float siluf(float v) { return v / (1.f + expf(-v)); }

static constexpr int Bb = 4, S = 2048, D = 1024, H = 2048, A = 128, E = 8;
static constexpr int N = Bb * S;

// async global->LDS, 16B per lane; LDS dest = wave-uniform base + lane*16
typedef __attribute__((address_space(1))) void gvoid;
typedef __attribute__((address_space(3))) void svoid;
__device__ __forceinline__ void gll16(const bf16_t* g, bf16_t* l) {
  __builtin_amdgcn_global_load_lds((gvoid*)g, (svoid*)l, 16, 0, 0);
}

// tiled-chunk element index: layout [R/TR][K/32][TR][4 chunks x 8], TR=128
// chunk slot p holds source chunk q = p ^ (r&3)  (XOR involution)
__device__ __forceinline__ long tidx(int row, int k, int K, int lgTR) {
  int TRm = (1 << lgTR) - 1;
  int q = (k >> 3) & 3;
  int p = q ^ (row & 3);
  return ((((long)(row >> lgTR) * (K >> 5) + (k >> 5)) << lgTR) + (row & TRm)) * 32 +
         ((long)p << 3);
}

// 8 consecutive f32 -> bf16 (plain round)
__device__ __forceinline__ bf16x8 ld8f(const float* p) {
  float4 a = *reinterpret_cast<const float4*>(p);
  float4 b = *reinterpret_cast<const float4*>(p + 4);
  bf16x8 r;
  r[0] = f2b(a.x); r[1] = f2b(a.y); r[2] = f2b(a.z); r[3] = f2b(a.w);
  r[4] = f2b(b.x); r[5] = f2b(b.y); r[6] = f2b(b.z); r[7] = f2b(b.w);
  return r;
}
// 8 consecutive f32 -> hi/lo bf16 split
__device__ __forceinline__ void split8(const float* p, bf16x8& h, bf16x8& l) {
  float4 a = *reinterpret_cast<const float4*>(p);
  float4 b = *reinterpret_cast<const float4*>(p + 4);
  float v[8] = {a.x, a.y, a.z, a.w, b.x, b.y, b.z, b.w};
#pragma unroll
  for (int j = 0; j < 8; j++) {
    bf16_t hh = f2b(v[j]);
    h[j] = hh;
    l[j] = f2b(v[j] - b2f(hh));
  }
}
// staging loader: 0 = bf16 row-major, 1 = f32 row-major, 2 = tiled bf16 TR=128
__device__ __forceinline__ bf16x8 ld8m(const void* p, int row, int k, int K, int m) {
  if (m == 1) return ld8f(reinterpret_cast<const float*>(p) + (long)row * K + k);
  if (m == 2)
    return *reinterpret_cast<const bf16x8*>(
        reinterpret_cast<const bf16_t*>(p) + tidx(row, k, K, 7));
  return *reinterpret_cast<const bf16x8*>(
      reinterpret_cast<const bf16_t*>(p) + (long)row * K + k);
}

// ---------------------------------------------------------------------------
// f32 -> hi/lo bf16 split into TILED chunk-swizzled layout.
// ---------------------------------------------------------------------------
template <int LGTR, int LGNKS>
__global__ __launch_bounds__(256) void split_tiled(
    const float* __restrict__ in, bf16_t* __restrict__ hi,
    bf16_t* __restrict__ lo, long total, int K) {
  long stride = (long)gridDim.x * 256;
  for (long o = (long)blockIdx.x * 256 + threadIdx.x; o < total; o += stride) {
    int p = (int)(o & 3);
    long t = o >> 2;
    int r = (int)(t & ((1 << LGTR) - 1));
    long t2 = t >> LGTR;
    int ks = (int)(t2 & ((1 << LGNKS) - 1));
    long rt = t2 >> LGNKS;
    long row = (rt << LGTR) + r;
    int k = (ks << 5) + ((p ^ (r & 3)) << 3);
    bf16x8 h, l;
    split8(in + row * K + k, h, l);
    reinterpret_cast<bf16x8*>(hi)[o] = h;
    reinterpret_cast<bf16x8*>(lo)[o] = l;
  }
}

// ---------------------------------------------------------------------------
// Plain-bf16 NT GEMM (verified layout).
// MODE: 0 bf16 store; 1 silu(clip(v,-5,5)) bf16; 2 f32 RMW C += 0.1*v;
//       3 f32 RMW C = C*aux[row] + 0.1*v;
//       4 TILED hi/lo bf16 RMW: s = (Ch+Cl) + 0.1*v; Ch,Cl = split(s)
// ---------------------------------------------------------------------------
template <int WM, int WN, int MODE>
__global__ __launch_bounds__(256) void gemm_nt_b(
    const void* __restrict__ Ag, const void* __restrict__ Bg,
    void* __restrict__ Cv, void* __restrict__ Cv2, int M, int Nn, int K,
    const float* __restrict__ aux, int aF, int bF) {
  constexpr int BM = 2 * WM, BN = 2 * WN, AM = WM / 16, AN = WN / 16;
  constexpr int LDT = 40;
  __shared__ alignas(16) bf16_t As[BM * LDT];
  __shared__ alignas(16) bf16_t Bs[BN * LDT];

  const int tid = threadIdx.x;
  const int wave = tid >> 6, lane = tid & 63;
  const int wr = wave >> 1, wc = wave & 1;
  const int quad = lane >> 4, l16 = lane & 15;
  const int rowA0 = blockIdx.y * BM, rowB0 = blockIdx.x * BN;

  f32x4 acc[AM][AN] = {};

  for (int k0 = 0; k0 < K; k0 += 32) {
    for (int c = tid; c < BM * 4; c += 256) {
      int r = c >> 2, kc = c & 3;
      *reinterpret_cast<bf16x8*>(&As[r * LDT + kc * 8]) =
          ld8m(Ag, rowA0 + r, k0 + kc * 8, K, aF);
    }
    for (int c = tid; c < BN * 4; c += 256) {
      int r = c >> 2, kc = c & 3;
      *reinterpret_cast<bf16x8*>(&Bs[r * LDT + kc * 8]) =
          ld8m(Bg, rowB0 + r, k0 + kc * 8, K, bF);
    }
    __syncthreads();
    bf16x8 af[AM], bfv[AN];
#pragma unroll
    for (int i = 0; i < AM; i++)
      af[i] = *reinterpret_cast<bf16x8*>(&As[(wr * WM + i * 16 + l16) * LDT + quad * 8]);
#pragma unroll
    for (int j = 0; j < AN; j++)
      bfv[j] = *reinterpret_cast<bf16x8*>(&Bs[(wc * WN + j * 16 + l16) * LDT + quad * 8]);
#pragma unroll
    for (int i = 0; i < AM; i++)
#pragma unroll
      for (int j = 0; j < AN; j++)
        acc[i][j] = __builtin_amdgcn_mfma_f32_16x16x32_bf16(af[i], bfv[j], acc[i][j], 0, 0, 0);
    __syncthreads();
  }

  // C/D: col = lane&15, row = quad*4 + reg
#pragma unroll
  for (int i = 0; i < AM; i++)
#pragma unroll
    for (int j = 0; j < AN; j++)
#pragma unroll
      for (int r = 0; r < 4; r++) {
        int row = rowA0 + wr * WM + i * 16 + quad * 4 + r;
        int col = rowB0 + wc * WN + j * 16 + l16;
        float v = acc[i][j][r];
        if constexpr (MODE == 0) {
          reinterpret_cast<bf16_t*>(Cv)[(long)row * Nn + col] = f2b(v);
        } else if constexpr (MODE == 1) {
          v = fminf(fmaxf(v, -5.f), 5.f);
          reinterpret_cast<bf16_t*>(Cv)[(long)row * Nn + col] = f2b(siluf(v));
        } else if constexpr (MODE == 2) {
          float* C = reinterpret_cast<float*>(Cv);
          long o = (long)row * Nn + col;
          C[o] = C[o] + 0.1f * v;
        } else if constexpr (MODE == 3) {
          float* C = reinterpret_cast<float*>(Cv);
          long o = (long)row * Nn + col;
          C[o] = C[o] * aux[row] + 0.1f * v;
        } else {
          bf16_t* Ch = reinterpret_cast<bf16_t*>(Cv);
          bf16_t* Cl = reinterpret_cast<bf16_t*>(Cv2);
          long o = tidx(row, col, Nn, 7) + (col & 7);
          float s = b2f(Ch[o]) + b2f(Cl[o]) + 0.1f * v;
          bf16_t hh = f2b(s);
          Ch[o] = hh;
          Cl[o] = f2b(s - b2f(hh));
        }
      }
}

// ---------------------------------------------------------------------------
// Fused gate/up from TILED pre-split inputs, global_load_lds staging.
// A tiles (x) TR=128: 8KB; B tiles (W) TR=64: 4KB. 8 gll16/wave/kstep.
// Epilogue writes hidden as TILED hi/lo pair (TR=128, K=H).
// ---------------------------------------------------------------------------
__global__ __launch_bounds__(256) void gemm_gu_g(
    const bf16_t* __restrict__ xhT, const bf16_t* __restrict__ xlT,
    const bf16_t* __restrict__ WghT, const bf16_t* __restrict__ WglT,
    const bf16_t* __restrict__ WuhT, const bf16_t* __restrict__ WulT,
    bf16_t* __restrict__ Hh, bf16_t* __restrict__ Hl) {
  __shared__ alignas(16) bf16_t Ah[128 * 32];
  __shared__ alignas(16) bf16_t Al[128 * 32];
  __shared__ alignas(16) bf16_t B1h[64 * 32];
  __shared__ alignas(16) bf16_t B1l[64 * 32];
  __shared__ alignas(16) bf16_t B2h[64 * 32];
  __shared__ alignas(16) bf16_t B2l[64 * 32];

  const int tid = threadIdx.x;
  const int wave = tid >> 6, lane = tid & 63;
  const int wr = wave >> 1, wc = wave & 1;
  const int quad = lane >> 4, l16 = lane & 15;
  const int sw = (quad ^ (l16 & 3)) << 3;  // swizzled chunk offset (elements)
  const int bm = blockIdx.y, bn = blockIdx.x;
  constexpr int nks = D / 32;

  f32x4 ag[4][2] = {}, au[4][2] = {};

  for (int ks = 0; ks < nks; ks++) {
    const int wo = wave << 9;  // wave slot offset, 512 elements = 1KB
    long ao = (((long)bm * nks + ks) << 12) + wo + lane * 8;
    long bo = (((long)bn * nks + ks) << 11) + wo + lane * 8;
    gll16(xhT + ao, Ah + wo);
    gll16(xhT + ao + 2048, Ah + wo + 2048);
    gll16(xlT + ao, Al + wo);
    gll16(xlT + ao + 2048, Al + wo + 2048);
    gll16(WghT + bo, B1h + wo);
    gll16(WglT + bo, B1l + wo);
    gll16(WuhT + bo, B2h + wo);
    gll16(WulT + bo, B2l + wo);
    __syncthreads();  // drains vmcnt (compiler-inserted) -> LDS ready
    bf16x8 afh[4], afl[4], b1h[2], b1l[2], b2h[2], b2l[2];
#pragma unroll
    for (int i = 0; i < 4; i++) {
      int ro = (wr * 64 + i * 16 + l16) * 32 + sw;
      afh[i] = *reinterpret_cast<bf16x8*>(&Ah[ro]);
      afl[i] = *reinterpret_cast<bf16x8*>(&Al[ro]);
    }
#pragma unroll
    for (int j = 0; j < 2; j++) {
      int ro = (wc * 32 + j * 16 + l16) * 32 + sw;
      b1h[j] = *reinterpret_cast<bf16x8*>(&B1h[ro]);
      b1l[j] = *reinterpret_cast<bf16x8*>(&B1l[ro]);
      b2h[j] = *reinterpret_cast<bf16x8*>(&B2h[ro]);
      b2l[j] = *reinterpret_cast<bf16x8*>(&B2l[ro]);
    }
#pragma unroll
    for (int i = 0; i < 4; i++)
#pragma unroll
      for (int j = 0; j < 2; j++) {
        ag[i][j] = __builtin_amdgcn_mfma_f32_16x16x32_bf16(afh[i], b1h[j], ag[i][j], 0, 0, 0);
        ag[i][j] = __builtin_amdgcn_mfma_f32_16x16x32_bf16(afh[i], b1l[j], ag[i][j], 0, 0, 0);
        ag[i][j] = __builtin_amdgcn_mfma_f32_16x16x32_bf16(afl[i], b1h[j], ag[i][j], 0, 0, 0);
        au[i][j] = __builtin_amdgcn_mfma_f32_16x16x32_bf16(afh[i], b2h[j], au[i][j], 0, 0, 0);
        au[i][j] = __builtin_amdgcn_mfma_f32_16x16x32_bf16(afh[i], b2l[j], au[i][j], 0, 0, 0);
        au[i][j] = __builtin_amdgcn_mfma_f32_16x16x32_bf16(afl[i], b2h[j], au[i][j], 0, 0, 0);
      }
    __syncthreads();  // all reads done before next-iter staging overwrites
  }

#pragma unroll
  for (int i = 0; i < 4; i++)
#pragma unroll
    for (int j = 0; j < 2; j++)
#pragma unroll
      for (int r = 0; r < 4; r++) {
        int row = bm * 128 + wr * 64 + i * 16 + quad * 4 + r;
        int col = bn * 64 + wc * 32 + j * 16 + l16;
        long o = tidx(row, col, H, 7) + (col & 7);
        float v = siluf(ag[i][j][r]) * au[i][j][r];
        bf16_t hh = f2b(v);
        Hh[o] = hh;
        Hl[o] = f2b(v - b2f(hh));
      }
}

// ---------------------------------------------------------------------------
// Down-proj from TILED pre-split inputs, global_load_lds staging (all 4).
// Tiles TR=128 (8KB each); 8 gll16/wave/kstep. Output f32 row-major.
// ---------------------------------------------------------------------------
__global__ __launch_bounds__(256) void gemm_dn_g(
    const bf16_t* __restrict__ HhT, const bf16_t* __restrict__ HlT,
    const bf16_t* __restrict__ WdhT, const bf16_t* __restrict__ WdlT,
    float* __restrict__ Cg) {
  __shared__ alignas(16) bf16_t Ah[128 * 32];
  __shared__ alignas(16) bf16_t Al[128 * 32];
  __shared__ alignas(16) bf16_t Bh[128 * 32];
  __shared__ alignas(16) bf16_t Bl[128 * 32];

  const int tid = threadIdx.x;
  const int wave = tid >> 6, lane = tid & 63;
  const int wr = wave >> 1, wc = wave & 1;
  const int quad = lane >> 4, l16 = lane & 15;
  const int sw = (quad ^ (l16 & 3)) << 3;
  const int by = blockIdx.y, bx = blockIdx.x;
  constexpr int nks = H / 32;

  f32x4 acc[4][4] = {};

  for (int ks = 0; ks < nks; ks++) {
    const int wo = wave << 9;
    long ao = (((long)by * nks + ks) << 12) + wo + lane * 8;
    long bo = (((long)bx * nks + ks) << 12) + wo + lane * 8;
    gll16(HhT + ao, Ah + wo);
    gll16(HhT + ao + 2048, Ah + wo + 2048);
    gll16(HlT + ao, Al + wo);
    gll16(HlT + ao + 2048, Al + wo + 2048);
    gll16(WdhT + bo, Bh + wo);
    gll16(WdhT + bo + 2048, Bh + wo + 2048);
    gll16(WdlT + bo, Bl + wo);
    gll16(WdlT + bo + 2048, Bl + wo + 2048);
    __syncthreads();
    bf16x8 afh[4], afl[4], bfh[4], bfl[4];
#pragma unroll
    for (int i = 0; i < 4; i++) {
      int ro = (wr * 64 + i * 16 + l16) * 32 + sw;
      afh[i] = *reinterpret_cast<bf16x8*>(&Ah[ro]);
      afl[i] = *reinterpret_cast<bf16x8*>(&Al[ro]);
    }
#pragma unroll
    for (int j = 0; j < 4; j++) {
      int ro = (wc * 64 + j * 16 + l16) * 32 + sw;
      bfh[j] = *reinterpret_cast<bf16x8*>(&Bh[ro]);
      bfl[j] = *reinterpret_cast<bf16x8*>(&Bl[ro]);
    }
#pragma unroll
    for (int i = 0; i < 4; i++)
#pragma unroll
      for (int j = 0; j < 4; j++) {
        acc[i][j] = __builtin_amdgcn_mfma_f32_16x16x32_bf16(afh[i], bfh[j], acc[i][j], 0, 0, 0);
        acc[i][j] = __builtin_amdgcn_mfma_f32_16x16x32_bf16(afh[i], bfl[j], acc[i][j], 0, 0, 0);
        acc[i][j] = __builtin_amdgcn_mfma_f32_16x16x32_bf16(afl[i], bfh[j], acc[i][j], 0, 0, 0);
      }
    __syncthreads();
  }

#pragma unroll
  for (int i = 0; i < 4; i++)
#pragma unroll
    for (int j = 0; j < 4; j++)
#pragma unroll
      for (int r = 0; r < 4; r++) {
        int row = by * 128 + wr * 64 + i * 16 + quad * 4 + r;
        int col = bx * 128 + wc * 64 + j * 16 + l16;
        Cg[(long)row * D + col] = acc[i][j][r];
      }
}

// ---------------------------------------------------------------------------
// Fused adapt attention (per batch): adpre = silu(clip(ai@ao^T)) @ ai
// ---------------------------------------------------------------------------
__global__ __launch_bounds__(256) void fused_adapt(
    const bf16_t* __restrict__ aib, const bf16_t* __restrict__ aob,
    const bf16_t* __restrict__ aiT, bf16_t* __restrict__ adpre) {
  constexpr int LDQ = 136;
  constexpr int LDP = 72;
  __shared__ alignas(16) bf16_t Qs[64 * LDQ];
  __shared__ alignas(16) bf16_t Os[64 * LDQ];
  __shared__ alignas(16) bf16_t Ps[64 * LDP];
  __shared__ alignas(16) bf16_t Vs[128 * LDP];

  const int tid = threadIdx.x;
  const int wave = tid >> 6, lane = tid & 63;
  const int wr = wave >> 1, wc = wave & 1;
  const int quad = lane >> 4, l16 = lane & 15;
  const int b = blockIdx.y;
  const int q0 = blockIdx.x * 64;

  for (int c = tid; c < 1024; c += 256) {
    int r = c >> 4, cc = c & 15;
    *reinterpret_cast<bf16x8*>(&Qs[r * LDQ + cc * 8]) =
        *reinterpret_cast<const bf16x8*>(&aib[((long)b * S + q0 + r) * A + cc * 8]);
  }

  f32x4 o[2][4] = {};

  for (int tt = 0; tt < S / 64; tt++) {
    const int t0 = tt * 64;
    __syncthreads();
    for (int c = tid; c < 1024; c += 256) {
      int r = c >> 4, cc = c & 15;
      *reinterpret_cast<bf16x8*>(&Os[r * LDQ + cc * 8]) =
          *reinterpret_cast<const bf16x8*>(&aob[((long)b * S + t0 + r) * A + cc * 8]);
    }
    for (int c = tid; c < 1024; c += 256) {
      int r = c >> 3, cc = c & 7;
      *reinterpret_cast<bf16x8*>(&Vs[r * LDP + cc * 8]) =
          *reinterpret_cast<const bf16x8*>(&aiT[((long)b * A + r) * S + t0 + cc * 8]);
    }
    __syncthreads();
    f32x4 p[2][2] = {};
#pragma unroll
    for (int ks = 0; ks < 4; ks++) {
      bf16x8 af[2], bfv[2];
#pragma unroll
      for (int i = 0; i < 2; i++)
        af[i] = *reinterpret_cast<bf16x8*>(&Qs[(wr * 32 + i * 16 + l16) * LDQ + ks * 32 + quad * 8]);
#pragma unroll
      for (int j = 0; j < 2; j++)
        bfv[j] = *reinterpret_cast<bf16x8*>(&Os[(wc * 32 + j * 16 + l16) * LDQ + ks * 32 + quad * 8]);
#pragma unroll
      for (int i = 0; i < 2; i++)
#pragma unroll
        for (int j = 0; j < 2; j++)
          p[i][j] = __builtin_amdgcn_mfma_f32_16x16x32_bf16(af[i], bfv[j], p[i][j], 0, 0, 0);
    }
#pragma unroll
    for (int i = 0; i < 2; i++)
#pragma unroll
      for (int j = 0; j < 2; j++)
#pragma unroll
        for (int r = 0; r < 4; r++) {
          int row = wr * 32 + i * 16 + quad * 4 + r;
          int col = wc * 32 + j * 16 + l16;
          float v = fminf(fmaxf(p[i][j][r], -5.f), 5.f);
          Ps[row * LDP + col] = f2b(siluf(v));
        }
    __syncthreads();
#pragma unroll
    for (int ks = 0; ks < 2; ks++) {
      bf16x8 paf[2], vbf[4];
#pragma unroll
      for (int i = 0; i < 2; i++)
        paf[i] = *reinterpret_cast<bf16x8*>(&Ps[(wr * 32 + i * 16 + l16) * LDP + ks * 32 + quad * 8]);
#pragma unroll
      for (int j = 0; j < 4; j++)
        vbf[j] = *reinterpret_cast<bf16x8*>(&Vs[(wc * 64 + j * 16 + l16) * LDP + ks * 32 + quad * 8]);
#pragma unroll
      for (int i = 0; i < 2; i++)
#pragma unroll
        for (int j = 0; j < 4; j++)
          o[i][j] = __builtin_amdgcn_mfma_f32_16x16x32_bf16(paf[i], vbf[j], o[i][j], 0, 0, 0);
    }
  }

#pragma unroll
  for (int i = 0; i < 2; i++)
#pragma unroll
    for (int j = 0; j < 4; j++)
#pragma unroll
      for (int r = 0; r < 4; r++) {
        int row = q0 + wr * 32 + i * 16 + quad * 4 + r;
        int col = wc * 64 + j * 16 + l16;
        adpre[((long)b * S + row) * A + col] = f2b(o[i][j][r]);
      }
}

// ---------------------------------------------------------------------------
// Mb = Wop @ WepT^T, split-K x8 into f32 partials.
// ---------------------------------------------------------------------------
__global__ __launch_bounds__(256) void gemm_mb_splitk(
    const float* __restrict__ Ag, const bf16_t* __restrict__ Bg,
    float* __restrict__ Mp, int M, int Nn, int K) {
  constexpr int BM = 64, BN = 64, LDT = 40;
  __shared__ alignas(16) bf16_t As[BM * LDT];
  __shared__ alignas(16) bf16_t Bs[BN * LDT];
  const int tid = threadIdx.x;
  const int wave = tid >> 6, lane = tid & 63;
  const int wr = wave >> 1, wc = wave & 1;
  const int quad = lane >> 4, l16 = lane & 15;
  const int rowA0 = blockIdx.y * BM, rowB0 = blockIdx.x * BN;
  const int kz = blockIdx.z;
  const int ks0 = kz * (K / 8), ks1 = ks0 + K / 8;

  f32x4 acc[2][2] = {};
  for (int k0 = ks0; k0 < ks1; k0 += 32) {
    for (int c = tid; c < BM * 4; c += 256) {
      int r = c >> 2, kc = c & 3;
      *reinterpret_cast<bf16x8*>(&As[r * LDT + kc * 8]) =
          ld8f(Ag + (long)(rowA0 + r) * K + k0 + kc * 8);
    }
    for (int c = tid; c < BN * 4; c += 256) {
      int r = c >> 2, kc = c & 3;
      *reinterpret_cast<bf16x8*>(&Bs[r * LDT + kc * 8]) =
          *reinterpret_cast<const bf16x8*>(&Bg[(long)(rowB0 + r) * K + k0 + kc * 8]);
    }
    __syncthreads();
    bf16x8 af[2], bfv[2];
#pragma unroll
    for (int i = 0; i < 2; i++)
      af[i] = *reinterpret_cast<bf16x8*>(&As[(wr * 32 + i * 16 + l16) * LDT + quad * 8]);
#pragma unroll
    for (int j = 0; j < 2; j++)
      bfv[j] = *reinterpret_cast<bf16x8*>(&Bs[(wc * 32 + j * 16 + l16) * LDT + quad * 8]);
#pragma unroll
    for (int i = 0; i < 2; i++)
#pragma unroll
      for (int j = 0; j < 2; j++)
        acc[i][j] = __builtin_amdgcn_mfma_f32_16x16x32_bf16(af[i], bfv[j], acc[i][j], 0, 0, 0);
    __syncthreads();
  }
#pragma unroll
  for (int i = 0; i < 2; i++)
#pragma unroll
    for (int j = 0; j < 2; j++)
#pragma unroll
      for (int r = 0; r < 4; r++) {
        int row = rowA0 + wr * 32 + i * 16 + quad * 4 + r;
        int col = rowB0 + wc * 32 + j * 16 + l16;
        Mp[(long)kz * M * Nn + (long)row * Nn + col] = acc[i][j][r];
      }
}

__global__ __launch_bounds__(256) void mb_combine(
    const float* __restrict__ Mp, bf16_t* __restrict__ Mb, int total) {
  int i = blockIdx.x * 256 + threadIdx.x;
  if (i >= total) return;
  float s = 0.f;
#pragma unroll
  for (int z = 0; z < 8; z++) s += Mp[(long)z * total + i];
  Mb[i] = f2b(s);
}

// ---------------------------------------------------------------------------
// Fallback-path kernels (f32 inputs, in-loop split) — unchanged, proven.
// ---------------------------------------------------------------------------
__global__ __launch_bounds__(256) void gemm_dn_hl(
    const float* __restrict__ Ag, const float* __restrict__ Bg,
    float* __restrict__ Cg, int M, int Nn, int K) {
  constexpr int BM = 128, BN = 128, LDT = 40;
  __shared__ alignas(16) bf16_t Ah[BM * LDT];
  __shared__ alignas(16) bf16_t Al[BM * LDT];
  __shared__ alignas(16) bf16_t Bh[BN * LDT];
  __shared__ alignas(16) bf16_t Bl[BN * LDT];

  const int tid = threadIdx.x;
  const int wave = tid >> 6, lane = tid & 63;
  const int wr = wave >> 1, wc = wave & 1;
  const int quad = lane >> 4, l16 = lane & 15;
  const int rowA0 = blockIdx.y * BM, rowB0 = blockIdx.x * BN;

  f32x4 acc[4][4] = {};

  for (int k0 = 0; k0 < K; k0 += 32) {
    for (int c = tid; c < BM * 4; c += 256) {
      int r = c >> 2, kc = c & 3;
      bf16x8 h, l;
      split8(&Ag[(long)(rowA0 + r) * K + k0 + kc * 8], h, l);
      *reinterpret_cast<bf16x8*>(&Ah[r * LDT + kc * 8]) = h;
      *reinterpret_cast<bf16x8*>(&Al[r * LDT + kc * 8]) = l;
    }
    for (int c = tid; c < BN * 4; c += 256) {
      int r = c >> 2, kc = c & 3;
      bf16x8 h, l;
      split8(&Bg[(long)(rowB0 + r) * K + k0 + kc * 8], h, l);
      *reinterpret_cast<bf16x8*>(&Bh[r * LDT + kc * 8]) = h;
      *reinterpret_cast<bf16x8*>(&Bl[r * LDT + kc * 8]) = l;
    }
    __syncthreads();
    bf16x8 afh[4], afl[4], bfh[4], bfl[4];
#pragma unroll
    for (int i = 0; i < 4; i++) {
      int ro = (wr * 64 + i * 16 + l16) * LDT + quad * 8;
      afh[i] = *reinterpret_cast<bf16x8*>(&Ah[ro]);
      afl[i] = *reinterpret_cast<bf16x8*>(&Al[ro]);
    }
#pragma unroll
    for (int j = 0; j < 4; j++) {
      int ro = (wc * 64 + j * 16 + l16) * LDT + quad * 8;
      bfh[j] = *reinterpret_cast<bf16x8*>(&Bh[ro]);
      bfl[j] = *reinterpret_cast<bf16x8*>(&Bl[ro]);
    }
#pragma unroll
    for (int i = 0; i < 4; i++)
#pragma unroll
      for (int j = 0; j < 4; j++) {
        acc[i][j] = __builtin_amdgcn_mfma_f32_16x16x32_bf16(afh[i], bfh[j], acc[i][j], 0, 0, 0);
        acc[i][j] = __builtin_amdgcn_mfma_f32_16x16x32_bf16(afh[i], bfl[j], acc[i][j], 0, 0, 0);
        acc[i][j] = __builtin_amdgcn_mfma_f32_16x16x32_bf16(afl[i], bfh[j], acc[i][j], 0, 0, 0);
      }
    __syncthreads();
  }

#pragma unroll
  for (int i = 0; i < 4; i++)
#pragma unroll
    for (int j = 0; j < 4; j++)
#pragma unroll
      for (int r = 0; r < 4; r++) {
        int row = rowA0 + wr * 64 + i * 16 + quad * 4 + r;
        int col = rowB0 + wc * 64 + j * 16 + l16;
        Cg[(long)row * Nn + col] = acc[i][j][r];
      }
}

__global__ __launch_bounds__(256) void gemm_gu_hl(
    const float* __restrict__ x, const float* __restrict__ Wg,
    const float* __restrict__ Wu, float* __restrict__ Cg, int M, int Nn, int K) {
  constexpr int BM = 128, BN = 64, LDT = 40;
  __shared__ alignas(16) bf16_t Ah[BM * LDT];
  __shared__ alignas(16) bf16_t Al[BM * LDT];
  __shared__ alignas(16) bf16_t B1h[BN * LDT];
  __shared__ alignas(16) bf16_t B1l[BN * LDT];
  __shared__ alignas(16) bf16_t B2h[BN * LDT];
  __shared__ alignas(16) bf16_t B2l[BN * LDT];

  const int tid = threadIdx.x;
  const int wave = tid >> 6, lane = tid & 63;
  const int wr = wave >> 1, wc = wave & 1;
  const int quad = lane >> 4, l16 = lane & 15;
  const int rowA0 = blockIdx.y * BM, rowB0 = blockIdx.x * BN;

  f32x4 ag[4][2] = {}, au[4][2] = {};

  for (int k0 = 0; k0 < K; k0 += 32) {
    for (int c = tid; c < BM * 4; c += 256) {
      int r = c >> 2, kc = c & 3;
      bf16x8 h, l;
      split8(&x[(long)(rowA0 + r) * K + k0 + kc * 8], h, l);
      *reinterpret_cast<bf16x8*>(&Ah[r * LDT + kc * 8]) = h;
      *reinterpret_cast<bf16x8*>(&Al[r * LDT + kc * 8]) = l;
    }
    for (int c = tid; c < BN * 4; c += 256) {
      int r = c >> 2, kc = c & 3;
      long idx = (long)(rowB0 + r) * K + k0 + kc * 8;
      bf16x8 h, l;
      split8(&Wg[idx], h, l);
      *reinterpret_cast<bf16x8*>(&B1h[r * LDT + kc * 8]) = h;
      *reinterpret_cast<bf16x8*>(&B1l[r * LDT + kc * 8]) = l;
      split8(&Wu[idx], h, l);
      *reinterpret_cast<bf16x8*>(&B2h[r * LDT + kc * 8]) = h;
      *reinterpret_cast<bf16x8*>(&B2l[r * LDT + kc * 8]) = l;
    }
    __syncthreads();
    bf16x8 afh[4], afl[4], b1h[2], b1l[2], b2h[2], b2l[2];
#pragma unroll
    for (int i = 0; i < 4; i++) {
      int ro = (wr * 64 + i * 16 + l16) * LDT + quad * 8;
      afh[i] = *reinterpret_cast<bf16x8*>(&Ah[ro]);
      afl[i] = *reinterpret_cast<bf16x8*>(&Al[ro]);
    }
#pragma unroll
    for (int j = 0; j < 2; j++) {
      int ro = (wc * 32 + j * 16 + l16) * LDT + quad * 8;
      b1h[j] = *reinterpret_cast<bf16x8*>(&B1h[ro]);
      b1l[j] = *reinterpret_cast<bf16x8*>(&B1l[ro]);
      b2h[j] = *reinterpret_cast<bf16x8*>(&B2h[ro]);
      b2l[j] = *reinterpret_cast<bf16x8*>(&B2l[ro]);
    }
#pragma unroll
    for (int i = 0; i < 4; i++)
#pragma unroll
      for (int j = 0; j < 2; j++) {
        ag[i][j] = __builtin_amdgcn_mfma_f32_16x16x32_bf16(afh[i], b1h[j], ag[i][j], 0, 0, 0);
        ag[i][j] = __builtin_amdgcn_mfma_f32_16x16x32_bf16(afh[i], b1l[j], ag[i][j], 0, 0, 0);
        ag[i][j] = __builtin_amdgcn_mfma_f32_16x16x32_bf16(afl[i], b1h[j], ag[i][j], 0, 0, 0);
        au[i][j] = __builtin_amdgcn_mfma_f32_16x16x32_bf16(afh[i], b2h[j], au[i][j], 0, 0, 0);
        au[i][j] = __builtin_amdgcn_mfma_f32_16x16x32_bf16(afh[i], b2l[j], au[i][j], 0, 0, 0);
        au[i][j] = __builtin_amdgcn_mfma_f32_16x16x32_bf16(afl[i], b2h[j], au[i][j], 0, 0, 0);
      }
    __syncthreads();
  }

#pragma unroll
  for (int i = 0; i < 4; i++)
#pragma unroll
    for (int j = 0; j < 2; j++)
#pragma unroll
      for (int r = 0; r < 4; r++) {
        int row = rowA0 + wr * 64 + i * 16 + quad * 4 + r;
        int col = rowB0 + wc * 32 + j * 16 + l16;
        Cg[(long)row * Nn + col] = siluf(ag[i][j][r]) * au[i][j][r];
      }
}

// ---------------------------------------------------------------------------
// Router (no global atomics, per-block partials).
// ---------------------------------------------------------------------------
__global__ __launch_bounds__(256) void router_kernel(
    const float* __restrict__ x, const float* __restrict__ Wgr,
    const float* __restrict__ Wer, int* __restrict__ eidx,
    float* __restrict__ fw, float* __restrict__ wsum,
    float* __restrict__ lpart) {
  __shared__ float part[4][12];
  const int wv = threadIdx.x >> 6;
  const int lane = threadIdx.x & 63;
  const int token = blockIdx.x * 4 + wv;
  if (lane < 12) part[wv][lane] = 0.f;
  const float* xp = x + (long)token * D;
  float xr[16];
#pragma unroll
  for (int i = 0; i < 16; i++) xr[i] = xp[lane + i * 64];
  float dots[6];
#pragma unroll
  for (int w = 0; w < 6; w++) {
    const float* wp = (w < 2) ? (Wgr + (long)w * D) : (Wer + (long)(w - 2) * D);
    float s = 0.f;
#pragma unroll
    for (int i = 0; i < 16; i++) s += xr[i] * wp[lane + i * 64];
#pragma unroll
    for (int off = 32; off; off >>= 1) s += __shfl_xor(s, off);
    dots[w] = s;
  }
  if (lane == 0) {
    float gl0 = dots[0], gl1 = dots[1];
    float mg = fmaxf(gl0, gl1);
    float e0 = expf(gl0 - mg), e1 = expf(gl1 - mg);
    float inv = 1.f / (e0 + e1);
    float gp0 = e0 * inv, gp1 = e1 * inv;
    int gi = (gp1 > gp0) ? 1 : 0;
    float gw = gi ? gp1 : gp0;
    float el[4] = {dots[2], dots[3], dots[4], dots[5]};
    float me = fmaxf(fmaxf(el[0], el[1]), fmaxf(el[2], el[3]));
    float ep[4], es = 0.f;
#pragma unroll
    for (int j = 0; j < 4; j++) { ep[j] = expf(el[j] - me); es += ep[j]; }
    float inve = 1.f / es;
#pragma unroll
    for (int j = 0; j < 4; j++) ep[j] *= inve;
    int i1 = 0;
    for (int j = 1; j < 4; j++) if (ep[j] > ep[i1]) i1 = j;
    int i2 = (i1 == 0) ? 1 : 0;
    for (int j = 0; j < 4; j++) if (j != i1 && j != i2 && ep[j] > ep[i2]) i2 = j;
    float l1 = ep[i1], l2 = ep[i2];
    float ils = 1.f / (l1 + l2 + 1e-7f);
    float f1 = gw * l1 * ils, f2 = gw * l2 * ils;
    eidx[token * 2] = gi * 4 + i1;
    eidx[token * 2 + 1] = gi * 4 + i2;
    fw[token * 2] = f1;
    fw[token * 2 + 1] = f2;
    wsum[token] = f1 + f2;
    part[wv][gi * 4 + i1] = f1;
    part[wv][gi * 4 + i2] = f2;
    part[wv][8] = gl0 * gl0 + gl1 * gl1;
    part[wv][9] = el[0] * el[0] + el[1] * el[1] + el[2] * el[2] + el[3] * el[3];
  }
  __syncthreads();
  if (threadIdx.x < 12) {
    lpart[(long)blockIdx.x * 12 + threadIdx.x] =
        part[0][threadIdx.x] + part[1][threadIdx.x] +
        part[2][threadIdx.x] + part[3][threadIdx.x];
  }
}

// ---------------------------------------------------------------------------
// Row LayerNorm over A=128 (bf16 in ws, f32 g/b, bf16 out).
// ---------------------------------------------------------------------------
__global__ __launch_bounds__(256) void ln_rows(
    const bf16_t* __restrict__ in, const float* __restrict__ g,
    const float* __restrict__ b, bf16_t* __restrict__ out) {
  const int row = blockIdx.x * 4 + (threadIdx.x >> 6);
  const int lane = threadIdx.x & 63;
  const bf16_t* p = in + (long)row * A;
  float x0 = b2f(p[lane]), x1 = b2f(p[lane + 64]);
  float s = x0 + x1;
#pragma unroll
  for (int off = 32; off; off >>= 1) s += __shfl_xor(s, off);
  float mean = s * (1.f / 128.f);
  float d0 = x0 - mean, d1 = x1 - mean;
  float q = d0 * d0 + d1 * d1;
#pragma unroll
  for (int off = 32; off; off >>= 1) q += __shfl_xor(q, off);
  float r = rsqrtf(q * (1.f / 128.f) + 1e-5f);
  bf16_t* po = out + (long)row * A;
  po[lane] = f2b(d0 * r * g[lane] + b[lane]);
  po[lane + 64] = f2b(d1 * r * g[lane + 64] + b[lane + 64]);
}

// ---------------------------------------------------------------------------
// Transpose [z,R,C] -> [z,C,R], bf16 out; input f32 (isf=1) or bf16.
// ---------------------------------------------------------------------------
__global__ __launch_bounds__(256) void transpose2d(
    const void* __restrict__ in, bf16_t* __restrict__ out, int R, int C, int isf) {
  __shared__ bf16_t t[32][33];
  const long zb = blockIdx.z;
  const long ib = zb * (long)R * C;
  bf16_t* op = out + zb * (long)R * C;
  const int r0 = blockIdx.y * 32, c0 = blockIdx.x * 32;
  const int tx = threadIdx.x & 31, ty = threadIdx.x >> 5;
#pragma unroll
  for (int i = 0; i < 4; i++) {
    long idx = ib + (long)(r0 + ty + i * 8) * C + c0 + tx;
    t[ty + i * 8][tx] = isf ? f2b(reinterpret_cast<const float*>(in)[idx])
                            : reinterpret_cast<const bf16_t*>(in)[idx];
  }
  __syncthreads();
#pragma unroll
  for (int i = 0; i < 4; i++) op[(long)(c0 + ty + i * 8) * R + r0 + tx] = t[tx][ty + i * 8];
}

// ---------------------------------------------------------------------------
// Expert branch: coalesced via pre-transposed WeaT[e][a][c] (bf16).
// ---------------------------------------------------------------------------
__global__ __launch_bounds__(128) void expert_adapt(
    const bf16_t* __restrict__ h0, const bf16_t* __restrict__ WeaT,
    const float* __restrict__ ln_eg, const float* __restrict__ ln_eb,
    const int* __restrict__ eidx, const float* __restrict__ fw,
    bf16_t* __restrict__ hw) {
  const int n = blockIdx.x;
  const int c = threadIdx.x;
  __shared__ float h0s[128];
  __shared__ float red[4];
  h0s[c] = b2f(h0[(long)n * A + c]);
  __syncthreads();
  float out = 0.f;
  for (int k = 0; k < 2; k++) {
    int e = eidx[n * 2 + k];
    e = min(max(e, 0), E - 1);
    float w = fw[n * 2 + k];
    const bf16_t* Wc = WeaT + (long)e * A * A + c;
    float t = 0.f;
#pragma unroll 8
    for (int a = 0; a < 128; a++) t += b2f(Wc[(long)a * A]) * h0s[a];
    float s = t, q = t * t;
#pragma unroll
    for (int off = 32; off; off >>= 1) { s += __shfl_xor(s, off); q += __shfl_xor(q, off); }
    if ((c & 63) == 0) { red[(c >> 6) * 2] = s; red[(c >> 6) * 2 + 1] = q; }
    __syncthreads();
    float Sx = red[0] + red[2], Qx = red[1] + red[3];
    float mean = Sx * (1.f / 128.f);
    float var = Qx * (1.f / 128.f) - mean * mean;
    float r = rsqrtf(var + 1e-5f);
    out += w * ((t - mean) * r * ln_eg[e * A + c] + ln_eb[e * A + c]);
    __syncthreads();
  }
  hw[(long)n * A + c] = f2b(out);
}

// ---------------------------------------------------------------------------
// Loss finalize.
// ---------------------------------------------------------------------------
__global__ __launch_bounds__(256) void finalize_loss(
    const float* __restrict__ lpart, int nblk, float* __restrict__ outv) {
  float acc[10] = {};
  for (int b = threadIdx.x; b < nblk; b += 256) {
    const float* p = lpart + (long)b * 12;
#pragma unroll
    for (int c = 0; c < 10; c++) acc[c] += p[c];
  }
  __shared__ float red[10][4];
  const int lane = threadIdx.x & 63, wv = threadIdx.x >> 6;
#pragma unroll
  for (int c = 0; c < 10; c++) {
    float s = acc[c];
#pragma unroll
    for (int off = 32; off; off >>= 1) s += __shfl_xor(s, off);
    if (lane == 0) red[c][wv] = s;
  }
  __syncthreads();
  if (threadIdx.x == 0) {
    float loss[10];
#pragma unroll
    for (int c = 0; c < 10; c++)
      loss[c] = red[c][0] + red[c][1] + red[c][2] + red[c][3];
    float tl = 0.f;
    for (int e = 0; e < 8; e++) tl += loss[e];
    float target = tl / 8.f;
    float mse = 0.f;
    for (int e = 0; e < 8; e++) { float d = loss[e] - target; mse += d * d; }
    mse *= (1.f / 8.f);
    outv[0] = 0.001f * (mse + loss[8] / (float)(N * 2) + loss[9] / (float)(N * 4));
  }
}

// ---------------------------------------------------------------------------
extern "C" void kernel_launch(void* const* d_in, const int* in_sizes, int n_in,
                              void* d_out, int out_size, void* d_ws, size_t ws_size,
                              hipStream_t stream) {
  const float* x = (const float*)d_in[0];
  const float* Wu = (const float*)d_in[1];
  const float* Wg = (const float*)d_in[2];
  const float* Wd = (const float*)d_in[3];
  const float* Wpre = (const float*)d_in[4];
  const float* Wpost = (const float*)d_in[5];
  const float* ln_g = (const float*)d_in[6];
  const float* ln_b = (const float*)d_in[7];
  const float* Wap = (const float*)d_in[8];
  const float* Wea = (const float*)d_in[9];
  const float* ln_eg = (const float*)d_in[10];
  const float* ln_eb = (const float*)d_in[11];
  const float* Wep = (const float*)d_in[12];
  const float* Wop = (const float*)d_in[13];
  const float* Wgr = (const float*)d_in[14];
  const float* Wer = (const float*)d_in[15];
  float* out = (float*)d_out;

  char* ws = (char*)d_ws;
  size_t off = 0;
  auto alloc = [&](size_t bytes) { char* p = ws + off; off += (bytes + 255) & ~size_t(255); return p; };
  // Common allocations (~18.5 MB)
  float* lpart = (float*)alloc((size_t)(N / 4) * 12 * 4);
  float* wsum = (float*)alloc((size_t)N * 4);
  float* fwb = (float*)alloc((size_t)N * 2 * 4);
  int* eidx = (int*)alloc((size_t)N * 2 * 4);
  bf16_t* Mb = (bf16_t*)alloc((size_t)D * A * 2);
  float* Mp = (float*)alloc((size_t)8 * D * A * 4);
  bf16_t* WepT = (bf16_t*)alloc((size_t)H * A * 2);
  bf16_t* hwb = (bf16_t*)alloc((size_t)N * A * 2);
  bf16_t* h0b = (bf16_t*)alloc((size_t)N * A * 2);
  bf16_t* aib = (bf16_t*)alloc((size_t)N * A * 2);
  bf16_t* scrA = (bf16_t*)alloc((size_t)N * A * 2);
  bf16_t* aob = (bf16_t*)alloc((size_t)N * A * 2);
  bf16_t* adpreb = (bf16_t*)alloc((size_t)N * A * 2);
  bf16_t* WeaT = (bf16_t*)alloc((size_t)E * A * A * 2);
  bf16_t* aopre = scrA;
  bf16_t* aiT = scrA;

  // Big path: pre-split TILED hi/lo buffers (+120 MB).
  const bool big = ws_size >= ((size_t)140 << 20);
  float* hiddenF = nullptr;
  bf16_t *xh = nullptr, *xl = nullptr;
  bf16_t *Wgh = nullptr, *Wgl = nullptr, *Wuh = nullptr, *Wul = nullptr;
  bf16_t *Wdh = nullptr, *Wdl = nullptr, *Hh = nullptr, *Hl = nullptr;
  if (big) {
    xh = (bf16_t*)alloc((size_t)N * D * 2);
    xl = (bf16_t*)alloc((size_t)N * D * 2);
    Wgh = (bf16_t*)alloc((size_t)H * D * 2);
    Wgl = (bf16_t*)alloc((size_t)H * D * 2);
    Wuh = (bf16_t*)alloc((size_t)H * D * 2);
    Wul = (bf16_t*)alloc((size_t)H * D * 2);
    Wdh = (bf16_t*)alloc((size_t)D * H * 2);
    Wdl = (bf16_t*)alloc((size_t)D * H * 2);
    Hh = (bf16_t*)alloc((size_t)N * H * 2);
    Hl = (bf16_t*)alloc((size_t)N * H * 2);
  } else {
    hiddenF = (float*)alloc((size_t)N * H * 4);
  }
  (void)ws_size; (void)in_sizes; (void)n_in; (void)out_size;

  const dim3 blk(256);

  router_kernel<<<dim3(N / 4), blk, 0, stream>>>(x, Wgr, Wer, eidx, fwb, wsum, lpart);
  transpose2d<<<dim3(A / 32, A / 32, E), blk, 0, stream>>>(Wea, WeaT, A, A, 1);

  if (big) {
    // tiled splits: x TR=128 K=D(32 ksteps); Wg/Wu TR=64 K=D; Wd TR=128 K=H(64)
    split_tiled<7, 5><<<dim3(2048), blk, 0, stream>>>(x, xh, xl, (long)N * D / 8, D);
    split_tiled<6, 5><<<dim3(512), blk, 0, stream>>>(Wg, Wgh, Wgl, (long)H * D / 8, D);
    split_tiled<6, 5><<<dim3(512), blk, 0, stream>>>(Wu, Wuh, Wul, (long)H * D / 8, D);
    split_tiled<7, 6><<<dim3(512), blk, 0, stream>>>(Wd, Wdh, Wdl, (long)D * H / 8, H);
    // hidden (tiled Hh/Hl) = silu(x@Wg^T)*(x@Wu^T)  [N,H] K=D
    gemm_gu_g<<<dim3(H / 64, N / 128), blk, 0, stream>>>(
        xh, xl, Wgh, Wgl, Wuh, Wul, Hh, Hl);
    // h0 = x@Wpre^T  [N,A] K=D  (A from tiled xh, aF=2)
    gemm_nt_b<16, 32, 0><<<dim3(A / 64, N / 32), blk, 0, stream>>>(
        xh, Wpre, h0b, nullptr, N, A, D, nullptr, 2, 1);
    ln_rows<<<dim3(N / 4), blk, 0, stream>>>(h0b, ln_g, ln_b, aib);
    // ao_pre = hidden@Wpost^T  [N,A] K=H  (A from tiled Hh, aF=2)
    gemm_nt_b<16, 32, 0><<<dim3(A / 64, N / 32), blk, 0, stream>>>(
        Hh, Wpost, aopre, nullptr, N, A, H, nullptr, 2, 1);
    ln_rows<<<dim3(N / 4), blk, 0, stream>>>(aopre, ln_g, ln_b, aob);
    transpose2d<<<dim3(A / 32, S / 32, Bb), blk, 0, stream>>>(aib, aiT, S, A, 0);
    fused_adapt<<<dim3(S / 64, Bb), blk, 0, stream>>>(aib, aob, aiT, adpreb);
    // hidden += 0.1 * adpre@Wap^T  (TILED hi/lo RMW, MODE 4)
    gemm_nt_b<64, 64, 4><<<dim3(H / 128, N / 128), blk, 0, stream>>>(
        adpreb, Wap, Hh, Hl, N, H, A, nullptr, 0, 1);
    // out = hidden@Wd^T  (all-gll16 staging from tiled operands)
    gemm_dn_g<<<dim3(D / 128, N / 128), blk, 0, stream>>>(Hh, Hl, Wdh, Wdl, out);
  } else {
    gemm_gu_hl<<<dim3(H / 64, N / 128), blk, 0, stream>>>(x, Wg, Wu, hiddenF, N, H, D);
    gemm_nt_b<16, 32, 0><<<dim3(A / 64, N / 32), blk, 0, stream>>>(
        x, Wpre, h0b, nullptr, N, A, D, nullptr, 1, 1);
    ln_rows<<<dim3(N / 4), blk, 0, stream>>>(h0b, ln_g, ln_b, aib);
    gemm_nt_b<16, 32, 0><<<dim3(A / 64, N / 32), blk, 0, stream>>>(
        hiddenF, Wpost, aopre, nullptr, N, A, H, nullptr, 1, 1);
    ln_rows<<<dim3(N / 4), blk, 0, stream>>>(aopre, ln_g, ln_b, aob);
    transpose2d<<<dim3(A / 32, S / 32, Bb), blk, 0, stream>>>(aib, aiT, S, A, 0);
    fused_adapt<<<dim3(S / 64, Bb), blk, 0, stream>>>(aib, aob, aiT, adpreb);
    gemm_nt_b<64, 64, 2><<<dim3(H / 128, N / 128), blk, 0, stream>>>(
        adpreb, Wap, hiddenF, nullptr, N, H, A, nullptr, 0, 1);
    gemm_dn_hl<<<dim3(D / 128, N / 128), blk, 0, stream>>>(hiddenF, Wd, out, N, D, H);
  }

  // Common tail
  transpose2d<<<dim3(A / 32, H / 32, 1), blk, 0, stream>>>(Wep, WepT, H, A, 1);
  gemm_mb_splitk<<<dim3(A / 64, D / 64, 8), blk, 0, stream>>>(
      Wop, WepT, Mp, D, A, H);
  mb_combine<<<dim3((D * A + 255) / 256), blk, 0, stream>>>(Mp, Mb, D * A);
  expert_adapt<<<dim3(N), dim3(128), 0, stream>>>(h0b, WeaT, ln_eg, ln_eb, eidx, fwb, hwb);
  gemm_nt_b<64, 64, 3><<<dim3(D / 128, N / 128), blk, 0, stream>>>(
      hwb, Mb, out, nullptr, N, D, A, wsum, 0, 0);
  finalize_loss<<<dim3(1), blk, 0, stream>>>(lpart, N / 4, out + (size_t)N * D);
}